// Round 10
// baseline (309.533 us; speedup 1.0000x reference)
//
#include <hip/hip_runtime.h>

// B=64, Cin=P=64, H=W=64, mid C=16, offsets C=18, K=3x3.  BN n = 262144
#define BN_N 262144.0f

typedef unsigned short u16;
typedef __attribute__((ext_vector_type(8))) short short8;   // 8 x bf16
typedef __attribute__((ext_vector_type(4))) float floatx4;

// xp: padded NHWC bf16, 64 ch/px, XOR-swizzled 16B chunks. Row pitch 66*64.
#define RP1 4224
#define IS1 278784          // 66*RP1
// h2p/h3p: padded NHWC bf16, 16 ch/px padded to 24 (2-way LDS banks). Row pitch 66*24.
#define RP2 1584
#define IS2 104544          // 66*RP2
#define H2P_TOTAL 6690816   // 64*IS2 u16

static __device__ __forceinline__ u16 f2bf(float f) {
  union { float f; unsigned u; } v; v.f = f;
  unsigned u = v.u;
  return (u16)((u + 0x7FFFu + ((u >> 16) & 1u)) >> 16);
}
static __device__ __forceinline__ float bf2f(u16 h) {
  union { unsigned u; float f; } v; v.u = ((unsigned)h) << 16;
  return v.f;
}
// async global->LDS, 16 B per lane; LDS dest = wave-uniform base + lane*16
static __device__ __forceinline__ void cp16(const u16* g, u16* l) {
  __builtin_amdgcn_global_load_lds((const __attribute__((address_space(1))) unsigned int*)g,
                                   (__attribute__((address_space(3))) unsigned int*)l, 16, 0, 0);
}

// ---------------------------------------------------------------- prep: x -> padded swizzled bf16  +  all weights (merged launch)
// Blocks 0..4223: prep_x (yp = blk%66, b = blk/66).  Blocks 4224..4437:
// weight repack (early return, no barrier crossed).
__global__ __launch_bounds__(256) void prep_all_k(const float* __restrict__ x,
                                                  u16* __restrict__ xp,
                                                  const float* __restrict__ w1,
                                                  const float* __restrict__ w4,
                                                  const float* __restrict__ w3,
                                                  const float* __restrict__ ow,
                                                  u16* __restrict__ Bsw, u16* __restrict__ Bsw4,
                                                  u16* __restrict__ Bsw3, u16* __restrict__ BswO) {
  int blk = blockIdx.x, tid = threadIdx.x;
  if (blk >= 4224) {                       // ---- weight repack blocks ----
    int wb = blk - 4224;
    if (wb < 144) {                        // conv1: K=576, 36864 elems
      int d = wb * 256 + tid;
      int kin = d & 7, n = (d >> 3) & 63, kgrp = (d >> 9) & 3, kc = d >> 11;
      int k = kc * 32 + kgrp * 8 + kin;
      int tap = k >> 6, c = k & 63;
      Bsw[d] = f2bf(w1[n * 576 + c * 9 + tap]);
    } else if (wb < 184) {                 // conv4: K=144->160, 10240 elems
      int d = (wb - 144) * 256 + tid;
      int kin = d & 7, n = (d >> 3) & 63, lkk = (d >> 9) & 3, kk = d >> 11;
      int tap = kk * 2 + (lkk >> 1);
      int c = ((lkk & 1) << 3) + kin;
      float v = (tap < 9) ? w4[n * 144 + c * 9 + tap] : 0.f;
      Bsw4[d] = f2bf(v);
    } else if (wb < 194) {                 // deform w3: 2560 elems
      int d = (wb - 184) * 256 + tid;
      int kin = d & 7, n = (d >> 3) & 15, lkk = (d >> 7) & 3, kk = d >> 9;
      int k = kk * 32 + lkk * 8 + kin;
      int tap = k >> 4, c = k & 15;
      float v = (tap < 9) ? w3[n * 144 + c * 9 + tap] : 0.f;
      Bsw3[d] = f2bf(v);
    } else {                               // offconv: 5120 elems
      int d = (wb - 194) * 256 + tid;
      int kin = d & 7, n = (d >> 3) & 31, lkk = (d >> 8) & 3, kk = d >> 10;
      int tap = kk * 2 + (lkk >> 1);
      int c = ((lkk & 1) << 3) + kin;
      float v = (tap < 9 && n < 18) ? ow[n * 144 + c * 9 + tap] : 0.f;
      BswO[d] = f2bf(v);
    }
    return;
  }
  // ---- prep_x blocks ----
  int yp = blk % 66;
  int b = blk / 66;
  u16* rowbase = xp + (size_t)(b * 66 + yp) * RP1;
  if (yp == 0 || yp == 65) {
    for (int i = tid; i < RP1 / 4; i += 256)
      ((ushort4*)rowbase)[i] = make_ushort4(0, 0, 0, 0);
    return;
  }
  int y = yp - 1;
  __shared__ __align__(16) u16 s[64][72];
  for (int i = tid; i < 4096; i += 256) {
    int c = i >> 6, xx = i & 63;
    s[xx][c] = f2bf(x[((b * 64 + c) << 12) + (y << 6) + xx]);
  }
  if (tid < 128) {                 // zero pad columns (px 0 and 65)
    int c = tid & 63;
    int pxp = (tid >> 6) ? 65 : 0;
    rowbase[pxp * 64 + c] = 0;
  }
  __syncthreads();
  for (int j = tid; j < 512; j += 256) {       // 64 px x 8 chunks of 16 B
    int xx = j >> 3, chunk = j & 7;
    int pxp = xx + 1;
    int ph = chunk ^ (pxp & 7);
    *(short8*)(rowbase + pxp * 64 + ph * 8) = *(const short8*)(&s[xx][chunk * 8]);
  }
}

// ---------------------------------------------------------------- conv1: persistent ring pipeline, 8 waves (2/SIMD), B in regs
__global__ __launch_bounds__(512, 2) void conv1_mfma(const u16* __restrict__ xp,
                                                     const u16* __restrict__ Bsw,
                                                     u16* __restrict__ h1,        // bf16 NCHW raw
                                                     float* __restrict__ sum1, float* __restrict__ sq1) {
  __shared__ __align__(16) u16 ring[43520];   // 5 slots x 8704 u16 (2 rows + 512B overread pad)
  __shared__ float LS[256], LQ[256];          // stats scratch [4 rows][64 oc]
  const int tid = threadIdx.x;
  const int w8 = tid >> 6, l = tid & 63;
  const int r = w8 & 3, g = w8 >> 2;          // row-in-tile, oc-half
  const int lm = l & 15, lk = l >> 4;
  const int b = blockIdx.x >> 2;
  const int quarter = blockIdx.x & 3;
  const int c0 = quarter * 8;                 // first 2-row chunk of this band
  const u16* xb = xp + (size_t)b * 66 * RP1;

  // B fragments -> registers, ONCE (oldest VMEM ops; prologue vmcnt(0) covers them)
  short8 bReg[18][2];
#pragma unroll
  for (int kk = 0; kk < 18; ++kk)
#pragma unroll
    for (int j = 0; j < 2; ++j)
      bReg[kk][j] = *(const short8*)(Bsw + (((kk * 4 + lk) * 64) + (g * 2 + j) * 16 + lm) * 8);

  // prologue: A chunks c0..c0+2 (3 x 17 segs); drain + barrier
#pragma unroll
  for (int c = 0; c < 3; ++c) {
    const u16* src = xb + (size_t)(2 * (c0 + c)) * RP1;
    u16* dst = ring + ((c0 + c) % 5) * 8704;
    for (int s = w8; s < 17; s += 8) cp16(src + s * 512 + l * 8, dst + s * 512);
  }
  asm volatile("s_waitcnt vmcnt(0)" ::: "memory");
  __builtin_amdgcn_s_barrier();
  __builtin_amdgcn_sched_barrier(0);

  float ssum[2] = {0.f, 0.f}, sqsm[2] = {0.f, 0.f};

#pragma unroll 1
  for (int j = 0; j < 4; ++j) {
    const int y0 = quarter * 16 + j * 4;
    // prefetch next tile's 2 new chunks (ring-5 liveness: disjoint slots)
    if (j < 3) {
#pragma unroll
      for (int c = 0; c < 2; ++c) {
        const int ch = c0 + 2 * j + 3 + c;
        const u16* src = xb + (size_t)(2 * ch) * RP1;
        u16* dst = ring + (ch % 5) * 8704;
        for (int s = w8; s < 17; s += 8) cp16(src + s * 512 + l * 8, dst + s * 512);
      }
      __builtin_amdgcn_sched_barrier(0);   // pin prefetch before stores
    }

    floatx4 acc[4][2];
#pragma unroll
    for (int mt = 0; mt < 4; ++mt)
#pragma unroll
      for (int nb = 0; nb < 2; ++nb)
        acc[mt][nb] = (floatx4){0.f, 0.f, 0.f, 0.f};

#pragma unroll
    for (int kk = 0; kk < 18; ++kk) {
      const int tap = kk >> 1;
      const int dy = (tap < 3) ? 0 : ((tap < 6) ? 1 : 2);
      const int dx = tap - dy * 3;
      const int chunk16 = ((kk & 1) << 2) + lk;   // logical 16B chunk 0..7
      const int pr = y0 + r + dy;                 // padded input row
      const u16* abase = ring + ((pr >> 1) % 5) * 8704 + (pr & 1) * 4224;
      short8 aF[4];
#pragma unroll
      for (int mt = 0; mt < 4; ++mt) {
        int pxp = mt * 16 + lm + dx;
        int ph = chunk16 ^ (pxp & 7);
        aF[mt] = *(const short8*)(abase + pxp * 64 + ph * 8);
      }
#pragma unroll
      for (int mt = 0; mt < 4; ++mt)
#pragma unroll
        for (int nb = 0; nb < 2; ++nb)
          acc[mt][nb] = __builtin_amdgcn_mfma_f32_16x16x32_bf16(aF[mt], bReg[kk][nb], acc[mt][nb], 0, 0, 0);
    }

    // store bf16 NCHW: oc = g*32 + nb*16 + lm, pixel x = mt*16 + lk*4 + reg (8 stores)
    const int y = y0 + r;
#pragma unroll
    for (int mt = 0; mt < 4; ++mt)
#pragma unroll
      for (int nb = 0; nb < 2; ++nb) {
        const int oc = g * 32 + nb * 16 + lm;
        u16* dst = h1 + ((size_t)(b * 64 + oc) << 12) + (y << 6) + mt * 16 + (lk << 2);
        floatx4 v = acc[mt][nb];
        *(ushort4*)dst = make_ushort4(f2bf(v.x), f2bf(v.y), f2bf(v.z), f2bf(v.w));
      }

    // per-tile stats into running registers
#pragma unroll
    for (int nb = 0; nb < 2; ++nb)
#pragma unroll
      for (int mt = 0; mt < 4; ++mt) {
        floatx4 a = acc[mt][nb];
        ssum[nb] += a.x + a.y + a.z + a.w;
        sqsm[nb] += a.x * a.x + a.y * a.y + a.z * a.z + a.w * a.w;
      }

    if (j < 3) {
      asm volatile("s_waitcnt vmcnt(8)" ::: "memory");
      __builtin_amdgcn_s_barrier();
      __builtin_amdgcn_sched_barrier(0);
    }
  }

  // final stats reduction (once per block)
#pragma unroll
  for (int nb = 0; nb < 2; ++nb) {
    ssum[nb] += __shfl_xor(ssum[nb], 16, 64);  ssum[nb] += __shfl_xor(ssum[nb], 32, 64);
    sqsm[nb] += __shfl_xor(sqsm[nb], 16, 64);  sqsm[nb] += __shfl_xor(sqsm[nb], 32, 64);
  }
  if (lk == 0) {
#pragma unroll
    for (int nb = 0; nb < 2; ++nb) {
      const int oc = g * 32 + nb * 16 + lm;
      LS[r * 64 + oc] = ssum[nb];  LQ[r * 64 + oc] = sqsm[nb];
    }
  }
  __syncthreads();
  if (tid < 64) atomicAdd(&sum1[tid], LS[tid] + LS[64 + tid] + LS[128 + tid] + LS[192 + tid]);
  else if (tid < 128) { int o = tid - 64; atomicAdd(&sq1[o], LQ[o] + LQ[64 + o] + LQ[128 + o] + LQ[192 + o]); }
}

// ---------------------------------------------------------------- conv2: 1x1 64->16 (bf16 h1 in), BN1+relu, bf16 NHWC out + stats2
__global__ __launch_bounds__(256) void conv2_k(const u16* __restrict__ h1,
                                               const float* __restrict__ w2,
                                               const float* __restrict__ sum1, const float* __restrict__ sq1,
                                               const float* __restrict__ g1, const float* __restrict__ b1,
                                               u16* __restrict__ out,          // bf16 NHWC (64,4096,16) raw
                                               float* __restrict__ sum2, float* __restrict__ sq2) {
  __shared__ float s_wt[64 * 16];
  __shared__ float s_scale[64], s_shift[64];
  __shared__ float ls[4][16], lsq[4][16];
  int tid = threadIdx.x;
  for (int i = tid; i < 1024; i += 256) {
    int o = i >> 6, c = i & 63;
    s_wt[c * 16 + o] = w2[i];
  }
  if (tid < 64) {
    float m = sum1[tid] / BN_N;
    float var = sq1[tid] / BN_N - m * m;
    float sc = g1[tid] * rsqrtf(var + 1e-5f);
    s_scale[tid] = sc;
    s_shift[tid] = b1[tid] - m * sc;
  }
  __syncthreads();
  int p = blockIdx.x * 256 + tid;
  int b = p >> 12, r = p & 4095;
  const u16* src = h1 + ((size_t)b << 18) + r;
  float acc[16];
#pragma unroll
  for (int o = 0; o < 16; ++o) acc[o] = 0.f;
  for (int c = 0; c < 64; ++c) {
    float v = bf2f(src[c << 12]);
    v = fmaxf(v * s_scale[c] + s_shift[c], 0.f);
    const float* wp = &s_wt[c * 16];
    float4 w0 = *(const float4*)wp;
    float4 w1 = *(const float4*)(wp + 4);
    float4 w2v = *(const float4*)(wp + 8);
    float4 w3v = *(const float4*)(wp + 12);
    acc[0] += w0.x * v;  acc[1] += w0.y * v;  acc[2] += w0.z * v;  acc[3] += w0.w * v;
    acc[4] += w1.x * v;  acc[5] += w1.y * v;  acc[6] += w1.z * v;  acc[7] += w1.w * v;
    acc[8] += w2v.x * v; acc[9] += w2v.y * v; acc[10] += w2v.z * v; acc[11] += w2v.w * v;
    acc[12] += w3v.x * v; acc[13] += w3v.y * v; acc[14] += w3v.z * v; acc[15] += w3v.w * v;
  }
  u16* dst = out + (size_t)p * 16;
  short8 o0, o1;
#pragma unroll
  for (int j = 0; j < 8; ++j) {
    o0[j] = (short)f2bf(acc[j]);
    o1[j] = (short)f2bf(acc[8 + j]);
  }
  *(short8*)(dst) = o0;
  *(short8*)(dst + 8) = o1;
  int lane = tid & 63, wv = tid >> 6;
#pragma unroll
  for (int o = 0; o < 16; ++o) {
    float s = acc[o], s2 = acc[o] * acc[o];
#pragma unroll
    for (int off = 32; off > 0; off >>= 1) {
      s += __shfl_down(s, off, 64);
      s2 += __shfl_down(s2, off, 64);
    }
    if (lane == 0) { ls[wv][o] = s; lsq[wv][o] = s2; }
  }
  __syncthreads();
  if (tid < 16) atomicAdd(&sum2[tid], ls[0][tid] + ls[1][tid] + ls[2][tid] + ls[3][tid]);
  else if (tid < 32) {
    int o = tid - 16;
    atomicAdd(&sq2[o], lsq[0][o] + lsq[1][o] + lsq[2][o] + lsq[3][o]);
  }
}

// ---------------------------------------------------------------- BN2+relu: bf16 NHWC raw -> padded pitch-24 bf16 h2p
__global__ __launch_bounds__(256) void bnrelu2_k(const u16* __restrict__ ws2,
                                                 const float* __restrict__ sum2, const float* __restrict__ sq2,
                                                 const float* __restrict__ g2, const float* __restrict__ b2,
                                                 u16* __restrict__ h2p) {
  __shared__ float s_scale[16], s_shift[16];
  int tid = threadIdx.x;
  if (tid < 16) {
    float m = sum2[tid] / BN_N;
    float var = sq2[tid] / BN_N - m * m;
    float sc = g2[tid] * rsqrtf(var + 1e-5f);
    s_scale[tid] = sc;
    s_shift[tid] = b2[tid] - m * sc;
  }
  __syncthreads();
  int p = blockIdx.x * 256 + tid;
  int b = p >> 12, r = p & 4095;
  int y = r >> 6, xx = r & 63;
  const u16* src = ws2 + (size_t)p * 16;
  short8 v0 = *(const short8*)(src);
  short8 v1 = *(const short8*)(src + 8);
  u16* dst = h2p + (size_t)(b * 66 + y + 1) * RP2 + (xx + 1) * 24;
  short8 o0, o1;
#pragma unroll
  for (int j = 0; j < 8; ++j) {
    o0[j] = (short)f2bf(fmaxf(bf2f((u16)v0[j]) * s_scale[j] + s_shift[j], 0.f));
    o1[j] = (short)f2bf(fmaxf(bf2f((u16)v1[j]) * s_scale[j + 8] + s_shift[j + 8], 0.f));
  }
  *(short8*)(dst) = o0;
  *(short8*)(dst + 8) = o1;
}

// ---------------------------------------------------------------- fused offconv + deform: offsets hand off via LDS (overlaid)
// offsT (20.5KB) OVERLAYS the dead lA/lB staging buffers after stage 1 ->
// LDS 50.7KB -> 30.2KB, so all 4 blocks/CU of the grid are co-resident
// (16 waves/CU vs ~7): the scattered bilinear gathers are latency-bound
// (R9 counters: MfmaUtil 1.9%, VALU 20%, HBM 3.5%, occ 22.8%) and need TLP.
__global__ __launch_bounds__(256, 5) void offdeform_mfma(const u16* __restrict__ h2p,
                                                         const u16* __restrict__ BswO,
                                                         const float* __restrict__ ob,
                                                         const u16* __restrict__ Bsw3,
                                                         u16* __restrict__ out,      // bf16 NHWC (64,4096,16) raw
                                                         float* __restrict__ sum3, float* __restrict__ sq3) {
  __shared__ __align__(16) u16 lmem[14848];  // lA[9728] | lB[5120]; offsT (20480B) overlays after stage 1
  __shared__ float ls[4][16], lsq[4][16];
  u16* lA = lmem;
  u16* lB = lmem + 9728;
  float* offsT = (float*)lmem;               // [(w*64+x)*20 + oc] after stage 1
  const int tid = threadIdx.x;
  const int w = tid >> 6, l = tid & 63;
  const int lm = l & 15, lk = l >> 4;
  const int b = blockIdx.x >> 4;
  const int y0 = (blockIdx.x & 15) << 2;
  const int y = y0 + w;
  const u16* src = h2p + ((size_t)b * 66 + y0) * RP2;
  for (int seg = w; seg < 19; seg += 4) cp16(src + seg * 512 + l * 8, lA + seg * 512);
  for (int seg = w; seg < 10; seg += 4) cp16(BswO + seg * 512 + l * 8, lB + seg * 512);
  __syncthreads();

  // ---- stage 1: offconv ----
  floatx4 acc[4][2];
#pragma unroll
  for (int mt = 0; mt < 4; ++mt)
#pragma unroll
    for (int nb = 0; nb < 2; ++nb)
      acc[mt][nb] = (floatx4){0.f, 0.f, 0.f, 0.f};

#pragma unroll
  for (int kk = 0; kk < 5; ++kk) {
    int tap = kk * 2 + (lk >> 1);
    if (tap > 8) tap = 8;
    const int dy = tap / 3, dx = tap - dy * 3;
    const int c0 = (lk & 1) << 3;
    const int rowoff = (w + dy) * RP2;
    short8 aF[4], bF[2];
#pragma unroll
    for (int mt = 0; mt < 4; ++mt)
      aF[mt] = *(const short8*)(lA + rowoff + (mt * 16 + lm + dx) * 24 + c0);
    const u16* bp = lB + (((kk * 4 + lk) * 32) + lm) * 8;
    bF[0] = *(const short8*)(bp);
    bF[1] = *(const short8*)(bp + 128);
#pragma unroll
    for (int mt = 0; mt < 4; ++mt)
#pragma unroll
      for (int nb = 0; nb < 2; ++nb)
        acc[mt][nb] = __builtin_amdgcn_mfma_f32_16x16x32_bf16(aF[mt], bF[nb], acc[mt][nb], 0, 0, 0);
  }
  __syncthreads();   // all waves done reading lA/lB -> safe to overlay offsT

  // offsets (+bias) -> LDS.  D layout: pixel x = mt*16 + lk*4 + reg, oc = nb*16+lm
#pragma unroll
  for (int mt = 0; mt < 4; ++mt)
#pragma unroll
    for (int nb = 0; nb < 2; ++nb) {
      int oc = nb * 16 + lm;
      if (oc < 18) {
        float bias = ob[oc];
        floatx4 v = acc[mt][nb];
#pragma unroll
        for (int reg = 0; reg < 4; ++reg)
          offsT[(w * 64 + mt * 16 + lk * 4 + reg) * 20 + oc] = v[reg] + bias;
      }
    }
  __syncthreads();

  // ---- stage 2: deform ----
  const u16* img = h2p + (size_t)b * IS2;
  short8 bf[5];
#pragma unroll
  for (int kk = 0; kk < 5; ++kk)
    bf[kk] = *(const short8*)(Bsw3 + (((kk * 4 + lk) * 16) + lm) * 8);

  floatx4 accd[4];
#pragma unroll
  for (int mt = 0; mt < 4; ++mt) accd[mt] = (floatx4){0.f, 0.f, 0.f, 0.f};

#pragma unroll
  for (int mt = 0; mt < 4; ++mt) {
    const int x = mt * 16 + lm;          // A-side pixel of this lane
#pragma unroll
    for (int kk = 0; kk < 5; ++kk) {
      const int k0 = kk * 32 + lk * 8;
      int tap = k0 >> 4;
      const int c0 = k0 & 15;
      if (tap > 8) tap = 8;
      const int dy = tap / 3, dx = tap - dy * 3;
      float offy = offsT[(w * 64 + x) * 20 + tap];
      float offx = offsT[(w * 64 + x) * 20 + tap + 9];
      float py = (float)(y + dy) + offy;
      float px = (float)(x + dx) + offx;
      py = fminf(fmaxf(py, 0.f), 65.f);
      px = fminf(fmaxf(px, 0.f), 65.f);
      float y0f = floorf(py), x0f = floorf(px);
      int yy0 = (int)y0f, xx0 = (int)x0f;
      int yy1 = min(yy0 + 1, 65), xx1 = min(xx0 + 1, 65);
      float wy = py - y0f, wx = px - x0f;
      float w00 = (1.f - wy) * (1.f - wx), w01 = (1.f - wy) * wx;
      float w10 = wy * (1.f - wx),         w11 = wy * wx;
      short8 v00 = *(const short8*)(img + (yy0 * 66 + xx0) * 24 + c0);
      short8 v01 = *(const short8*)(img + (yy0 * 66 + xx1) * 24 + c0);
      short8 v10 = *(const short8*)(img + (yy1 * 66 + xx0) * 24 + c0);
      short8 v11 = *(const short8*)(img + (yy1 * 66 + xx1) * 24 + c0);
      short8 a;
#pragma unroll
      for (int jj = 0; jj < 8; ++jj) {
        float s = bf2f((u16)v00[jj]) * w00 + bf2f((u16)v01[jj]) * w01
                + bf2f((u16)v10[jj]) * w10 + bf2f((u16)v11[jj]) * w11;
        a[jj] = (short)f2bf(s);
      }
      accd[mt] = __builtin_amdgcn_mfma_f32_16x16x32_bf16(a, bf[kk], accd[mt], 0, 0, 0);
    }
  }

  // store bf16 NHWC raw: pixel = mt*16 + lk*4 + reg, channel = lm; + stats
  const int pbase = (b << 12) + (y << 6);
  float s = 0.f, s2 = 0.f;
#pragma unroll
  for (int mt = 0; mt < 4; ++mt) {
    floatx4 a = accd[mt];
    s += a.x + a.y + a.z + a.w;
    s2 += a.x * a.x + a.y * a.y + a.z * a.z + a.w * a.w;
#pragma unroll
    for (int reg = 0; reg < 4; ++reg) {
      int pp = pbase + mt * 16 + lk * 4 + reg;
      out[(size_t)pp * 16 + lm] = f2bf(a[reg]);
    }
  }
  s += __shfl_xor(s, 16, 64);  s += __shfl_xor(s, 32, 64);
  s2 += __shfl_xor(s2, 16, 64); s2 += __shfl_xor(s2, 32, 64);
  if (lk == 0) { ls[w][lm] = s; lsq[w][lm] = s2; }
  __syncthreads();
  if (tid < 16) atomicAdd(&sum3[tid], ls[0][tid] + ls[1][tid] + ls[2][tid] + ls[3][tid]);
  else if (tid < 32) {
    int o = tid - 16;
    atomicAdd(&sq3[o], lsq[0][o] + lsq[1][o] + lsq[2][o] + lsq[3][o]);
  }
}

// ---------------------------------------------------------------- BN3+relu: bf16 NHWC raw -> padded pitch-24 bf16 h3p
__global__ __launch_bounds__(256) void bnrelu3_k(const u16* __restrict__ wsd,
                                                 const float* __restrict__ sum3, const float* __restrict__ sq3,
                                                 const float* __restrict__ g3, const float* __restrict__ b3,
                                                 u16* __restrict__ h3p) {
  __shared__ float s_scale[16], s_shift[16];
  int tid = threadIdx.x;
  if (tid < 16) {
    float m = sum3[tid] / BN_N;
    float var = sq3[tid] / BN_N - m * m;
    float sc = g3[tid] * rsqrtf(var + 1e-5f);
    s_scale[tid] = sc;
    s_shift[tid] = b3[tid] - m * sc;
  }
  __syncthreads();
  int p = blockIdx.x * 256 + tid;
  int b = p >> 12, r = p & 4095;
  int y = r >> 6, xx = r & 63;
  const u16* src = wsd + (size_t)p * 16;
  short8 v0 = *(const short8*)(src);
  short8 v1 = *(const short8*)(src + 8);
  u16* dst = h3p + (size_t)(b * 66 + y + 1) * RP2 + (xx + 1) * 24;
  short8 o0, o1;
#pragma unroll
  for (int j = 0; j < 8; ++j) {
    o0[j] = (short)f2bf(fmaxf(bf2f((u16)v0[j]) * s_scale[j] + s_shift[j], 0.f));
    o1[j] = (short)f2bf(fmaxf(bf2f((u16)v1[j]) * s_scale[j + 8] + s_shift[j + 8], 0.f));
  }
  *(short8*)(dst) = o0;
  *(short8*)(dst + 8) = o1;
}

// ---------------------------------------------------------------- conv4: LDS-staged implicit GEMM (A+B in LDS) + stats4
__global__ __launch_bounds__(256) void conv4_mfma(const u16* __restrict__ h3p,
                                                  const u16* __restrict__ Bsw4,
                                                  u16* __restrict__ h4,
                                                  float* __restrict__ sum4, float* __restrict__ sq4) {
  __shared__ __align__(16) u16 lA[9728];     // 19 segs
  __shared__ __align__(16) u16 lB[10240];    // 20 segs
  const int tid = threadIdx.x;
  const int w = tid >> 6, l = tid & 63;
  const int lm = l & 15, lk = l >> 4;
  const int b = blockIdx.x >> 4;
  const int y0 = (blockIdx.x & 15) << 2;
  const int y = y0 + w;
  const u16* src = h3p + ((size_t)b * 66 + y0) * RP2;
  for (int seg = w; seg < 19; seg += 4) cp16(src + seg * 512 + l * 8, lA + seg * 512);
  for (int seg = w; seg < 20; seg += 4) cp16(Bsw4 + seg * 512 + l * 8, lB + seg * 512);
  __syncthreads();

  floatx4 acc[4][4];
#pragma unroll
  for (int mt = 0; mt < 4; ++mt)
#pragma unroll
    for (int nb = 0; nb < 4; ++nb)
      acc[mt][nb] = (floatx4){0.f, 0.f, 0.f, 0.f};

#pragma unroll
  for (int kk = 0; kk < 5; ++kk) {
    int tap = kk * 2 + (lk >> 1);
    if (tap > 8) tap = 8;
    const int dy = tap / 3, dx = tap - dy * 3;
    const int c0 = (lk & 1) << 3;
    const int rowoff = (w + dy) * RP2;
    short8 aF[4], bF[4];
#pragma unroll
    for (int mt = 0; mt < 4; ++mt)
      aF[mt] = *(const short8*)(lA + rowoff + (mt * 16 + lm + dx) * 24 + c0);
    const u16* bp = lB + (((kk * 4 + lk) * 64) + lm) * 8;
    bF[0] = *(const short8*)(bp);
    bF[1] = *(const short8*)(bp + 128);
    bF[2] = *(const short8*)(bp + 256);
    bF[3] = *(const short8*)(bp + 384);
#pragma unroll
    for (int mt = 0; mt < 4; ++mt)
#pragma unroll
      for (int nb = 0; nb < 4; ++nb)
        acc[mt][nb] = __builtin_amdgcn_mfma_f32_16x16x32_bf16(aF[mt], bF[nb], acc[mt][nb], 0, 0, 0);
  }

#pragma unroll
  for (int mt = 0; mt < 4; ++mt)
#pragma unroll
    for (int nb = 0; nb < 4; ++nb) {
      u16* dst = h4 + ((size_t)(b * 64 + nb * 16 + lm) << 12) + (y << 6) + mt * 16 + (lk << 2);
      floatx4 v = acc[mt][nb];
      *(ushort4*)dst = make_ushort4(f2bf(v.x), f2bf(v.y), f2bf(v.z), f2bf(v.w));
    }

  // fused stats4 (reuse lA after barrier)
  __syncthreads();
  float* LS = (float*)lA;
  float* LQ = LS + 256;
  float s[4], s2[4];
#pragma unroll
  for (int nb = 0; nb < 4; ++nb) {
    s[nb] = 0.f; s2[nb] = 0.f;
#pragma unroll
    for (int mt = 0; mt < 4; ++mt) {
      floatx4 a = acc[mt][nb];
      s[nb] += a.x + a.y + a.z + a.w;
      s2[nb] += a.x * a.x + a.y * a.y + a.z * a.z + a.w * a.w;
    }
    s[nb] += __shfl_xor(s[nb], 16, 64);  s[nb] += __shfl_xor(s[nb], 32, 64);
    s2[nb] += __shfl_xor(s2[nb], 16, 64); s2[nb] += __shfl_xor(s2[nb], 32, 64);
  }
  if (lk == 0) {
#pragma unroll
    for (int nb = 0; nb < 4; ++nb) { LS[w * 64 + nb * 16 + lm] = s[nb]; LQ[w * 64 + nb * 16 + lm] = s2[nb]; }
  }
  __syncthreads();
  if (tid < 64) atomicAdd(&sum4[tid], LS[tid] + LS[64 + tid] + LS[128 + tid] + LS[192 + tid]);
  else if (tid < 128) { int o = tid - 64; atomicAdd(&sq4[o], LQ[o] + LQ[64 + o] + LQ[128 + o] + LQ[192 + o]); }
}

// ---------------------------------------------------------------- final: BN4 + residual + relu (h4 bf16 -> out fp32), grid-stride
__global__ __launch_bounds__(256) void final_k(const u16* __restrict__ h4,
                                               float* __restrict__ out,
                                               const float* __restrict__ x,
                                               const float* __restrict__ sum4, const float* __restrict__ sq4,
                                               const float* __restrict__ g4, const float* __restrict__ b4) {
  __shared__ float s_scale[64], s_shift[64];
  int tid = threadIdx.x;
  if (tid < 64) {
    float m = sum4[tid] / BN_N;
    float var = sq4[tid] / BN_N - m * m;
    float sc = g4[tid] * rsqrtf(var + 1e-5f);
    s_scale[tid] = sc;
    s_shift[tid] = b4[tid] - m * sc;
  }
  __syncthreads();
  // 16,777,216 floats = 4,194,304 float4; 2048 blocks x 256 thr -> 8 iters
  int t0 = blockIdx.x * 256 + tid;
#pragma unroll
  for (int it = 0; it < 8; ++it) {
    int i = (t0 + it * 524288) * 4;
    int c = (i >> 12) & 63;
    ushort4 q = *(const ushort4*)(h4 + i);
    float4 xv = *(const float4*)(x + i);
    float sc = s_scale[c], sh = s_shift[c];
    float4 v;
    v.x = fmaxf(bf2f(q.x) * sc + sh + xv.x, 0.f);
    v.y = fmaxf(bf2f(q.y) * sc + sh + xv.y, 0.f);
    v.z = fmaxf(bf2f(q.z) * sc + sh + xv.z, 0.f);
    v.w = fmaxf(bf2f(q.w) * sc + sh + xv.w, 0.f);
    *(float4*)(out + i) = v;
  }
}

extern "C" void kernel_launch(void* const* d_in, const int* in_sizes, int n_in,
                              void* d_out, int out_size, void* d_ws, size_t ws_size,
                              hipStream_t stream) {
  const float* x  = (const float*)d_in[0];
  const float* w1 = (const float*)d_in[1];
  const float* g1 = (const float*)d_in[2];
  const float* b1 = (const float*)d_in[3];
  const float* w2 = (const float*)d_in[4];
  const float* g2 = (const float*)d_in[5];
  const float* b2 = (const float*)d_in[6];
  const float* ow = (const float*)d_in[7];
  const float* ob = (const float*)d_in[8];
  const float* w3 = (const float*)d_in[9];
  const float* g3 = (const float*)d_in[10];
  const float* b3 = (const float*)d_in[11];
  const float* w4 = (const float*)d_in[12];
  const float* g4 = (const float*)d_in[13];
  const float* b4 = (const float*)d_in[14];
  float* out = (float*)d_out;
  float* ws = (float*)d_ws;

  // workspace layout (float offsets) — regions keep fp32-era sizes, some hold
  // bf16 (half-used):
  //   reg0 (ex-offs, 4,718,592 floats): h4 (bf16 NCHW conv4 raw) overlays
  //   wsd  region (4,194,304): bf16 NHWC deform raw (uses half)
  //   ws2  region (4,194,304): bf16 NHWC conv2 raw (uses half)
  //   h2p  region (4,460,544): padded pitch-24 bf16; h3p SHARES it
  //   stats 320
  //   Bsw(36864) Bsw4(10240) Bsw3(2560) BswO(5120)  u16
  // xp (swizzled bf16 input, 17.8M u16) overlays reg0+wsd+ws2 head; dead
  // after conv1.  h1 (bf16 NCHW conv1 raw) lives in d_out.
  float* reg0 = ws;
  float* wsd  = reg0 + 4718592;
  float* ws2  = wsd + 4194304;
  float* h2pf = ws2 + 4194304;
  float* stats = h2pf + 4460544;
  float* sum1 = stats, *sq1 = stats + 64;
  float* sum2 = stats + 128, *sq2 = stats + 144;
  float* sum3 = stats + 160, *sq3 = stats + 176;
  float* sum4 = stats + 192, *sq4 = stats + 256;
  u16* xp   = (u16*)ws;
  u16* Bsw  = (u16*)(stats + 320);
  u16* Bsw4 = Bsw + 36864;
  u16* Bsw3 = Bsw4 + 10240;
  u16* BswO = Bsw3 + 2560;
  u16* h2p  = (u16*)h2pf;    // bf16 padded pitch-24; doubles as h3p
  u16* h4   = (u16*)reg0;    // bf16 NCHW conv4 raw
  u16* h1   = (u16*)out;     // bf16 NCHW conv1 raw, in d_out
  u16* ws2b = (u16*)ws2;     // bf16 NHWC conv2 raw
  u16* wsdb = (u16*)wsd;     // bf16 NHWC deform raw

  hipMemsetAsync(stats, 0, 320 * sizeof(float), stream);
  hipMemsetAsync(h2p, 0, (size_t)H2P_TOTAL * sizeof(u16), stream);

  prep_all_k<<<4438, 256, 0, stream>>>(x, xp, w1, w4, w3, ow, Bsw, Bsw4, Bsw3, BswO);
  conv1_mfma<<<256, 512, 0, stream>>>(xp, Bsw, h1, sum1, sq1);
  conv2_k<<<1024, 256, 0, stream>>>(h1, w2, sum1, sq1, g1, b1, ws2b, sum2, sq2);
  bnrelu2_k<<<1024, 256, 0, stream>>>(ws2b, sum2, sq2, g2, b2, h2p);
  offdeform_mfma<<<1024, 256, 0, stream>>>(h2p, BswO, ob, Bsw3, wsdb, sum3, sq3);
  bnrelu3_k<<<1024, 256, 0, stream>>>(wsdb, sum3, sq3, g3, b3, h2p /* = h3p */);
  conv4_mfma<<<1024, 256, 0, stream>>>(h2p, Bsw4, h4, sum4, sq4);
  final_k<<<2048, 256, 0, stream>>>(h4, out, x, sum4, sq4, g4, b4);
}

// Round 11
// 308.819 us; speedup vs baseline: 1.0023x; 1.0023x over previous
//
#include <hip/hip_runtime.h>

// B=64, Cin=P=64, H=W=64, mid C=16, offsets C=18, K=3x3.  BN n = 262144
#define BN_N 262144.0f

typedef unsigned short u16;
typedef __attribute__((ext_vector_type(8))) short short8;   // 8 x bf16
typedef __attribute__((ext_vector_type(4))) float floatx4;

// xp: padded NHWC bf16, 64 ch/px, XOR-swizzled 16B chunks. Row pitch 66*64.
#define RP1 4224
#define IS1 278784          // 66*RP1
// h2p/h3p: padded NHWC bf16, 16 ch/px padded to 24 (2-way LDS banks). Row pitch 66*24.
#define RP2 1584
#define IS2 104544          // 66*RP2
#define H2P_TOTAL 6690816   // 64*IS2 u16

static __device__ __forceinline__ u16 f2bf(float f) {
  union { float f; unsigned u; } v; v.f = f;
  unsigned u = v.u;
  return (u16)((u + 0x7FFFu + ((u >> 16) & 1u)) >> 16);
}
static __device__ __forceinline__ float bf2f(u16 h) {
  union { unsigned u; float f; } v; v.u = ((unsigned)h) << 16;
  return v.f;
}
// async global->LDS, 16 B per lane; LDS dest = wave-uniform base + lane*16
static __device__ __forceinline__ void cp16(const u16* g, u16* l) {
  __builtin_amdgcn_global_load_lds((const __attribute__((address_space(1))) unsigned int*)g,
                                   (__attribute__((address_space(3))) unsigned int*)l, 16, 0, 0);
}

// ---------------------------------------------------------------- prep: x -> padded swizzled bf16  +  all weights (merged launch)
// Blocks 0..4223: prep_x (yp = blk%66, b = blk/66).  Blocks 4224..4437:
// weight repack (early return, no barrier crossed).
__global__ __launch_bounds__(256) void prep_all_k(const float* __restrict__ x,
                                                  u16* __restrict__ xp,
                                                  const float* __restrict__ w1,
                                                  const float* __restrict__ w4,
                                                  const float* __restrict__ w3,
                                                  const float* __restrict__ ow,
                                                  u16* __restrict__ Bsw, u16* __restrict__ Bsw4,
                                                  u16* __restrict__ Bsw3, u16* __restrict__ BswO) {
  int blk = blockIdx.x, tid = threadIdx.x;
  if (blk >= 4224) {                       // ---- weight repack blocks ----
    int wb = blk - 4224;
    if (wb < 144) {                        // conv1: K=576, 36864 elems
      int d = wb * 256 + tid;
      int kin = d & 7, n = (d >> 3) & 63, kgrp = (d >> 9) & 3, kc = d >> 11;
      int k = kc * 32 + kgrp * 8 + kin;
      int tap = k >> 6, c = k & 63;
      Bsw[d] = f2bf(w1[n * 576 + c * 9 + tap]);
    } else if (wb < 184) {                 // conv4: K=144->160, 10240 elems
      int d = (wb - 144) * 256 + tid;
      int kin = d & 7, n = (d >> 3) & 63, lkk = (d >> 9) & 3, kk = d >> 11;
      int tap = kk * 2 + (lkk >> 1);
      int c = ((lkk & 1) << 3) + kin;
      float v = (tap < 9) ? w4[n * 144 + c * 9 + tap] : 0.f;
      Bsw4[d] = f2bf(v);
    } else if (wb < 194) {                 // deform w3: 2560 elems
      int d = (wb - 184) * 256 + tid;
      int kin = d & 7, n = (d >> 3) & 15, lkk = (d >> 7) & 3, kk = d >> 9;
      int k = kk * 32 + lkk * 8 + kin;
      int tap = k >> 4, c = k & 15;
      float v = (tap < 9) ? w3[n * 144 + c * 9 + tap] : 0.f;
      Bsw3[d] = f2bf(v);
    } else {                               // offconv: 5120 elems
      int d = (wb - 194) * 256 + tid;
      int kin = d & 7, n = (d >> 3) & 31, lkk = (d >> 8) & 3, kk = d >> 10;
      int tap = kk * 2 + (lkk >> 1);
      int c = ((lkk & 1) << 3) + kin;
      float v = (tap < 9 && n < 18) ? ow[n * 144 + c * 9 + tap] : 0.f;
      BswO[d] = f2bf(v);
    }
    return;
  }
  // ---- prep_x blocks ----
  int yp = blk % 66;
  int b = blk / 66;
  u16* rowbase = xp + (size_t)(b * 66 + yp) * RP1;
  if (yp == 0 || yp == 65) {
    for (int i = tid; i < RP1 / 4; i += 256)
      ((ushort4*)rowbase)[i] = make_ushort4(0, 0, 0, 0);
    return;
  }
  int y = yp - 1;
  __shared__ __align__(16) u16 s[64][72];
  for (int i = tid; i < 4096; i += 256) {
    int c = i >> 6, xx = i & 63;
    s[xx][c] = f2bf(x[((b * 64 + c) << 12) + (y << 6) + xx]);
  }
  if (tid < 128) {                 // zero pad columns (px 0 and 65)
    int c = tid & 63;
    int pxp = (tid >> 6) ? 65 : 0;
    rowbase[pxp * 64 + c] = 0;
  }
  __syncthreads();
  for (int j = tid; j < 512; j += 256) {       // 64 px x 8 chunks of 16 B
    int xx = j >> 3, chunk = j & 7;
    int pxp = xx + 1;
    int ph = chunk ^ (pxp & 7);
    *(short8*)(rowbase + pxp * 64 + ph * 8) = *(const short8*)(&s[xx][chunk * 8]);
  }
}

// ---------------------------------------------------------------- conv1: persistent ring pipeline, 8 waves (2/SIMD), B in regs
__global__ __launch_bounds__(512, 2) void conv1_mfma(const u16* __restrict__ xp,
                                                     const u16* __restrict__ Bsw,
                                                     u16* __restrict__ h1,        // bf16 NCHW raw
                                                     float* __restrict__ sum1, float* __restrict__ sq1) {
  __shared__ __align__(16) u16 ring[43520];   // 5 slots x 8704 u16 (2 rows + 512B overread pad)
  __shared__ float LS[256], LQ[256];          // stats scratch [4 rows][64 oc]
  const int tid = threadIdx.x;
  const int w8 = tid >> 6, l = tid & 63;
  const int r = w8 & 3, g = w8 >> 2;          // row-in-tile, oc-half
  const int lm = l & 15, lk = l >> 4;
  const int b = blockIdx.x >> 2;
  const int quarter = blockIdx.x & 3;
  const int c0 = quarter * 8;                 // first 2-row chunk of this band
  const u16* xb = xp + (size_t)b * 66 * RP1;

  // B fragments -> registers, ONCE (oldest VMEM ops; prologue vmcnt(0) covers them)
  short8 bReg[18][2];
#pragma unroll
  for (int kk = 0; kk < 18; ++kk)
#pragma unroll
    for (int j = 0; j < 2; ++j)
      bReg[kk][j] = *(const short8*)(Bsw + (((kk * 4 + lk) * 64) + (g * 2 + j) * 16 + lm) * 8);

  // prologue: A chunks c0..c0+2 (3 x 17 segs); drain + barrier
#pragma unroll
  for (int c = 0; c < 3; ++c) {
    const u16* src = xb + (size_t)(2 * (c0 + c)) * RP1;
    u16* dst = ring + ((c0 + c) % 5) * 8704;
    for (int s = w8; s < 17; s += 8) cp16(src + s * 512 + l * 8, dst + s * 512);
  }
  asm volatile("s_waitcnt vmcnt(0)" ::: "memory");
  __builtin_amdgcn_s_barrier();
  __builtin_amdgcn_sched_barrier(0);

  float ssum[2] = {0.f, 0.f}, sqsm[2] = {0.f, 0.f};

#pragma unroll 1
  for (int j = 0; j < 4; ++j) {
    const int y0 = quarter * 16 + j * 4;
    // prefetch next tile's 2 new chunks (ring-5 liveness: disjoint slots)
    if (j < 3) {
#pragma unroll
      for (int c = 0; c < 2; ++c) {
        const int ch = c0 + 2 * j + 3 + c;
        const u16* src = xb + (size_t)(2 * ch) * RP1;
        u16* dst = ring + (ch % 5) * 8704;
        for (int s = w8; s < 17; s += 8) cp16(src + s * 512 + l * 8, dst + s * 512);
      }
      __builtin_amdgcn_sched_barrier(0);   // pin prefetch before stores
    }

    floatx4 acc[4][2];
#pragma unroll
    for (int mt = 0; mt < 4; ++mt)
#pragma unroll
      for (int nb = 0; nb < 2; ++nb)
        acc[mt][nb] = (floatx4){0.f, 0.f, 0.f, 0.f};

#pragma unroll
    for (int kk = 0; kk < 18; ++kk) {
      const int tap = kk >> 1;
      const int dy = (tap < 3) ? 0 : ((tap < 6) ? 1 : 2);
      const int dx = tap - dy * 3;
      const int chunk16 = ((kk & 1) << 2) + lk;   // logical 16B chunk 0..7
      const int pr = y0 + r + dy;                 // padded input row
      const u16* abase = ring + ((pr >> 1) % 5) * 8704 + (pr & 1) * 4224;
      short8 aF[4];
#pragma unroll
      for (int mt = 0; mt < 4; ++mt) {
        int pxp = mt * 16 + lm + dx;
        int ph = chunk16 ^ (pxp & 7);
        aF[mt] = *(const short8*)(abase + pxp * 64 + ph * 8);
      }
#pragma unroll
      for (int mt = 0; mt < 4; ++mt)
#pragma unroll
        for (int nb = 0; nb < 2; ++nb)
          acc[mt][nb] = __builtin_amdgcn_mfma_f32_16x16x32_bf16(aF[mt], bReg[kk][nb], acc[mt][nb], 0, 0, 0);
    }

    // store bf16 NCHW: oc = g*32 + nb*16 + lm, pixel x = mt*16 + lk*4 + reg (8 stores)
    const int y = y0 + r;
#pragma unroll
    for (int mt = 0; mt < 4; ++mt)
#pragma unroll
      for (int nb = 0; nb < 2; ++nb) {
        const int oc = g * 32 + nb * 16 + lm;
        u16* dst = h1 + ((size_t)(b * 64 + oc) << 12) + (y << 6) + mt * 16 + (lk << 2);
        floatx4 v = acc[mt][nb];
        *(ushort4*)dst = make_ushort4(f2bf(v.x), f2bf(v.y), f2bf(v.z), f2bf(v.w));
      }

    // per-tile stats into running registers
#pragma unroll
    for (int nb = 0; nb < 2; ++nb)
#pragma unroll
      for (int mt = 0; mt < 4; ++mt) {
        floatx4 a = acc[mt][nb];
        ssum[nb] += a.x + a.y + a.z + a.w;
        sqsm[nb] += a.x * a.x + a.y * a.y + a.z * a.z + a.w * a.w;
      }

    if (j < 3) {
      asm volatile("s_waitcnt vmcnt(8)" ::: "memory");
      __builtin_amdgcn_s_barrier();
      __builtin_amdgcn_sched_barrier(0);
    }
  }

  // final stats reduction (once per block)
#pragma unroll
  for (int nb = 0; nb < 2; ++nb) {
    ssum[nb] += __shfl_xor(ssum[nb], 16, 64);  ssum[nb] += __shfl_xor(ssum[nb], 32, 64);
    sqsm[nb] += __shfl_xor(sqsm[nb], 16, 64);  sqsm[nb] += __shfl_xor(sqsm[nb], 32, 64);
  }
  if (lk == 0) {
#pragma unroll
    for (int nb = 0; nb < 2; ++nb) {
      const int oc = g * 32 + nb * 16 + lm;
      LS[r * 64 + oc] = ssum[nb];  LQ[r * 64 + oc] = sqsm[nb];
    }
  }
  __syncthreads();
  if (tid < 64) atomicAdd(&sum1[tid], LS[tid] + LS[64 + tid] + LS[128 + tid] + LS[192 + tid]);
  else if (tid < 128) { int o = tid - 64; atomicAdd(&sq1[o], LQ[o] + LQ[64 + o] + LQ[128 + o] + LQ[192 + o]); }
}

// ---------------------------------------------------------------- conv2: 1x1 64->16 (bf16 h1 in), BN1+relu, bf16 NHWC out + stats2
__global__ __launch_bounds__(256) void conv2_k(const u16* __restrict__ h1,
                                               const float* __restrict__ w2,
                                               const float* __restrict__ sum1, const float* __restrict__ sq1,
                                               const float* __restrict__ g1, const float* __restrict__ b1,
                                               u16* __restrict__ out,          // bf16 NHWC (64,4096,16) raw
                                               float* __restrict__ sum2, float* __restrict__ sq2) {
  __shared__ float s_wt[64 * 16];
  __shared__ float s_scale[64], s_shift[64];
  __shared__ float ls[4][16], lsq[4][16];
  int tid = threadIdx.x;
  for (int i = tid; i < 1024; i += 256) {
    int o = i >> 6, c = i & 63;
    s_wt[c * 16 + o] = w2[i];
  }
  if (tid < 64) {
    float m = sum1[tid] / BN_N;
    float var = sq1[tid] / BN_N - m * m;
    float sc = g1[tid] * rsqrtf(var + 1e-5f);
    s_scale[tid] = sc;
    s_shift[tid] = b1[tid] - m * sc;
  }
  __syncthreads();
  int p = blockIdx.x * 256 + tid;
  int b = p >> 12, r = p & 4095;
  const u16* src = h1 + ((size_t)b << 18) + r;
  float acc[16];
#pragma unroll
  for (int o = 0; o < 16; ++o) acc[o] = 0.f;
  for (int c = 0; c < 64; ++c) {
    float v = bf2f(src[c << 12]);
    v = fmaxf(v * s_scale[c] + s_shift[c], 0.f);
    const float* wp = &s_wt[c * 16];
    float4 w0 = *(const float4*)wp;
    float4 w1 = *(const float4*)(wp + 4);
    float4 w2v = *(const float4*)(wp + 8);
    float4 w3v = *(const float4*)(wp + 12);
    acc[0] += w0.x * v;  acc[1] += w0.y * v;  acc[2] += w0.z * v;  acc[3] += w0.w * v;
    acc[4] += w1.x * v;  acc[5] += w1.y * v;  acc[6] += w1.z * v;  acc[7] += w1.w * v;
    acc[8] += w2v.x * v; acc[9] += w2v.y * v; acc[10] += w2v.z * v; acc[11] += w2v.w * v;
    acc[12] += w3v.x * v; acc[13] += w3v.y * v; acc[14] += w3v.z * v; acc[15] += w3v.w * v;
  }
  u16* dst = out + (size_t)p * 16;
  short8 o0, o1;
#pragma unroll
  for (int j = 0; j < 8; ++j) {
    o0[j] = (short)f2bf(acc[j]);
    o1[j] = (short)f2bf(acc[8 + j]);
  }
  *(short8*)(dst) = o0;
  *(short8*)(dst + 8) = o1;
  int lane = tid & 63, wv = tid >> 6;
#pragma unroll
  for (int o = 0; o < 16; ++o) {
    float s = acc[o], s2 = acc[o] * acc[o];
#pragma unroll
    for (int off = 32; off > 0; off >>= 1) {
      s += __shfl_down(s, off, 64);
      s2 += __shfl_down(s2, off, 64);
    }
    if (lane == 0) { ls[wv][o] = s; lsq[wv][o] = s2; }
  }
  __syncthreads();
  if (tid < 16) atomicAdd(&sum2[tid], ls[0][tid] + ls[1][tid] + ls[2][tid] + ls[3][tid]);
  else if (tid < 32) {
    int o = tid - 16;
    atomicAdd(&sq2[o], lsq[0][o] + lsq[1][o] + lsq[2][o] + lsq[3][o]);
  }
}

// ---------------------------------------------------------------- BN2+relu: bf16 NHWC raw -> padded pitch-24 bf16 h2p
__global__ __launch_bounds__(256) void bnrelu2_k(const u16* __restrict__ ws2,
                                                 const float* __restrict__ sum2, const float* __restrict__ sq2,
                                                 const float* __restrict__ g2, const float* __restrict__ b2,
                                                 u16* __restrict__ h2p) {
  __shared__ float s_scale[16], s_shift[16];
  int tid = threadIdx.x;
  if (tid < 16) {
    float m = sum2[tid] / BN_N;
    float var = sq2[tid] / BN_N - m * m;
    float sc = g2[tid] * rsqrtf(var + 1e-5f);
    s_scale[tid] = sc;
    s_shift[tid] = b2[tid] - m * sc;
  }
  __syncthreads();
  int p = blockIdx.x * 256 + tid;
  int b = p >> 12, r = p & 4095;
  int y = r >> 6, xx = r & 63;
  const u16* src = ws2 + (size_t)p * 16;
  short8 v0 = *(const short8*)(src);
  short8 v1 = *(const short8*)(src + 8);
  u16* dst = h2p + (size_t)(b * 66 + y + 1) * RP2 + (xx + 1) * 24;
  short8 o0, o1;
#pragma unroll
  for (int j = 0; j < 8; ++j) {
    o0[j] = (short)f2bf(fmaxf(bf2f((u16)v0[j]) * s_scale[j] + s_shift[j], 0.f));
    o1[j] = (short)f2bf(fmaxf(bf2f((u16)v1[j]) * s_scale[j + 8] + s_shift[j + 8], 0.f));
  }
  *(short8*)(dst) = o0;
  *(short8*)(dst + 8) = o1;
}

// ---------------------------------------------------------------- fused offconv + deform: offsets hand off via LDS (overlaid)
// offsT (20.5KB) OVERLAYS the dead lA/lB staging buffers after stage 1 ->
// LDS 50.7KB -> 30.2KB -> 5 blocks/CU by LDS.  NO __launch_bounds__ occupancy
// pin: R10's (256,5) squeezed VGPR 68->48, spilling ~20 regs to scratch, and
// per-wave scratch allocation throttled residency to ~1.7% (134us).  Natural
// 68-VGPR allocation already permits 5+ blocks; let LDS be the limiter.
__global__ __launch_bounds__(256) void offdeform_mfma(const u16* __restrict__ h2p,
                                                      const u16* __restrict__ BswO,
                                                      const float* __restrict__ ob,
                                                      const u16* __restrict__ Bsw3,
                                                      u16* __restrict__ out,      // bf16 NHWC (64,4096,16) raw
                                                      float* __restrict__ sum3, float* __restrict__ sq3) {
  __shared__ __align__(16) u16 lmem[14848];  // lA[9728] | lB[5120]; offsT (20480B) overlays after stage 1
  __shared__ float ls[4][16], lsq[4][16];
  u16* lA = lmem;
  u16* lB = lmem + 9728;
  float* offsT = (float*)lmem;               // [(w*64+x)*20 + oc] after stage 1
  const int tid = threadIdx.x;
  const int w = tid >> 6, l = tid & 63;
  const int lm = l & 15, lk = l >> 4;
  const int b = blockIdx.x >> 4;
  const int y0 = (blockIdx.x & 15) << 2;
  const int y = y0 + w;
  const u16* src = h2p + ((size_t)b * 66 + y0) * RP2;
  for (int seg = w; seg < 19; seg += 4) cp16(src + seg * 512 + l * 8, lA + seg * 512);
  for (int seg = w; seg < 10; seg += 4) cp16(BswO + seg * 512 + l * 8, lB + seg * 512);
  __syncthreads();

  // ---- stage 1: offconv ----
  floatx4 acc[4][2];
#pragma unroll
  for (int mt = 0; mt < 4; ++mt)
#pragma unroll
    for (int nb = 0; nb < 2; ++nb)
      acc[mt][nb] = (floatx4){0.f, 0.f, 0.f, 0.f};

#pragma unroll
  for (int kk = 0; kk < 5; ++kk) {
    int tap = kk * 2 + (lk >> 1);
    if (tap > 8) tap = 8;
    const int dy = tap / 3, dx = tap - dy * 3;
    const int c0 = (lk & 1) << 3;
    const int rowoff = (w + dy) * RP2;
    short8 aF[4], bF[2];
#pragma unroll
    for (int mt = 0; mt < 4; ++mt)
      aF[mt] = *(const short8*)(lA + rowoff + (mt * 16 + lm + dx) * 24 + c0);
    const u16* bp = lB + (((kk * 4 + lk) * 32) + lm) * 8;
    bF[0] = *(const short8*)(bp);
    bF[1] = *(const short8*)(bp + 128);
#pragma unroll
    for (int mt = 0; mt < 4; ++mt)
#pragma unroll
      for (int nb = 0; nb < 2; ++nb)
        acc[mt][nb] = __builtin_amdgcn_mfma_f32_16x16x32_bf16(aF[mt], bF[nb], acc[mt][nb], 0, 0, 0);
  }
  __syncthreads();   // all waves done reading lA/lB -> safe to overlay offsT

  // offsets (+bias) -> LDS.  D layout: pixel x = mt*16 + lk*4 + reg, oc = nb*16+lm
#pragma unroll
  for (int mt = 0; mt < 4; ++mt)
#pragma unroll
    for (int nb = 0; nb < 2; ++nb) {
      int oc = nb * 16 + lm;
      if (oc < 18) {
        float bias = ob[oc];
        floatx4 v = acc[mt][nb];
#pragma unroll
        for (int reg = 0; reg < 4; ++reg)
          offsT[(w * 64 + mt * 16 + lk * 4 + reg) * 20 + oc] = v[reg] + bias;
      }
    }
  __syncthreads();

  // ---- stage 2: deform ----
  const u16* img = h2p + (size_t)b * IS2;
  short8 bf[5];
#pragma unroll
  for (int kk = 0; kk < 5; ++kk)
    bf[kk] = *(const short8*)(Bsw3 + (((kk * 4 + lk) * 16) + lm) * 8);

  floatx4 accd[4];
#pragma unroll
  for (int mt = 0; mt < 4; ++mt) accd[mt] = (floatx4){0.f, 0.f, 0.f, 0.f};

#pragma unroll
  for (int mt = 0; mt < 4; ++mt) {
    const int x = mt * 16 + lm;          // A-side pixel of this lane
#pragma unroll
    for (int kk = 0; kk < 5; ++kk) {
      const int k0 = kk * 32 + lk * 8;
      int tap = k0 >> 4;
      const int c0 = k0 & 15;
      if (tap > 8) tap = 8;
      const int dy = tap / 3, dx = tap - dy * 3;
      float offy = offsT[(w * 64 + x) * 20 + tap];
      float offx = offsT[(w * 64 + x) * 20 + tap + 9];
      float py = (float)(y + dy) + offy;
      float px = (float)(x + dx) + offx;
      py = fminf(fmaxf(py, 0.f), 65.f);
      px = fminf(fmaxf(px, 0.f), 65.f);
      float y0f = floorf(py), x0f = floorf(px);
      int yy0 = (int)y0f, xx0 = (int)x0f;
      int yy1 = min(yy0 + 1, 65), xx1 = min(xx0 + 1, 65);
      float wy = py - y0f, wx = px - x0f;
      float w00 = (1.f - wy) * (1.f - wx), w01 = (1.f - wy) * wx;
      float w10 = wy * (1.f - wx),         w11 = wy * wx;
      short8 v00 = *(const short8*)(img + (yy0 * 66 + xx0) * 24 + c0);
      short8 v01 = *(const short8*)(img + (yy0 * 66 + xx1) * 24 + c0);
      short8 v10 = *(const short8*)(img + (yy1 * 66 + xx0) * 24 + c0);
      short8 v11 = *(const short8*)(img + (yy1 * 66 + xx1) * 24 + c0);
      short8 a;
#pragma unroll
      for (int jj = 0; jj < 8; ++jj) {
        float s = bf2f((u16)v00[jj]) * w00 + bf2f((u16)v01[jj]) * w01
                + bf2f((u16)v10[jj]) * w10 + bf2f((u16)v11[jj]) * w11;
        a[jj] = (short)f2bf(s);
      }
      accd[mt] = __builtin_amdgcn_mfma_f32_16x16x32_bf16(a, bf[kk], accd[mt], 0, 0, 0);
    }
  }

  // store bf16 NHWC raw: pixel = mt*16 + lk*4 + reg, channel = lm; + stats
  const int pbase = (b << 12) + (y << 6);
  float s = 0.f, s2 = 0.f;
#pragma unroll
  for (int mt = 0; mt < 4; ++mt) {
    floatx4 a = accd[mt];
    s += a.x + a.y + a.z + a.w;
    s2 += a.x * a.x + a.y * a.y + a.z * a.z + a.w * a.w;
#pragma unroll
    for (int reg = 0; reg < 4; ++reg) {
      int pp = pbase + mt * 16 + lk * 4 + reg;
      out[(size_t)pp * 16 + lm] = f2bf(a[reg]);
    }
  }
  s += __shfl_xor(s, 16, 64);  s += __shfl_xor(s, 32, 64);
  s2 += __shfl_xor(s2, 16, 64); s2 += __shfl_xor(s2, 32, 64);
  if (lk == 0) { ls[w][lm] = s; lsq[w][lm] = s2; }
  __syncthreads();
  if (tid < 16) atomicAdd(&sum3[tid], ls[0][tid] + ls[1][tid] + ls[2][tid] + ls[3][tid]);
  else if (tid < 32) {
    int o = tid - 16;
    atomicAdd(&sq3[o], lsq[0][o] + lsq[1][o] + lsq[2][o] + lsq[3][o]);
  }
}

// ---------------------------------------------------------------- BN3+relu: bf16 NHWC raw -> padded pitch-24 bf16 h3p
__global__ __launch_bounds__(256) void bnrelu3_k(const u16* __restrict__ wsd,
                                                 const float* __restrict__ sum3, const float* __restrict__ sq3,
                                                 const float* __restrict__ g3, const float* __restrict__ b3,
                                                 u16* __restrict__ h3p) {
  __shared__ float s_scale[16], s_shift[16];
  int tid = threadIdx.x;
  if (tid < 16) {
    float m = sum3[tid] / BN_N;
    float var = sq3[tid] / BN_N - m * m;
    float sc = g3[tid] * rsqrtf(var + 1e-5f);
    s_scale[tid] = sc;
    s_shift[tid] = b3[tid] - m * sc;
  }
  __syncthreads();
  int p = blockIdx.x * 256 + tid;
  int b = p >> 12, r = p & 4095;
  int y = r >> 6, xx = r & 63;
  const u16* src = wsd + (size_t)p * 16;
  short8 v0 = *(const short8*)(src);
  short8 v1 = *(const short8*)(src + 8);
  u16* dst = h3p + (size_t)(b * 66 + y + 1) * RP2 + (xx + 1) * 24;
  short8 o0, o1;
#pragma unroll
  for (int j = 0; j < 8; ++j) {
    o0[j] = (short)f2bf(fmaxf(bf2f((u16)v0[j]) * s_scale[j] + s_shift[j], 0.f));
    o1[j] = (short)f2bf(fmaxf(bf2f((u16)v1[j]) * s_scale[j + 8] + s_shift[j + 8], 0.f));
  }
  *(short8*)(dst) = o0;
  *(short8*)(dst + 8) = o1;
}

// ---------------------------------------------------------------- conv4: LDS-staged implicit GEMM (A+B in LDS) + stats4
__global__ __launch_bounds__(256) void conv4_mfma(const u16* __restrict__ h3p,
                                                  const u16* __restrict__ Bsw4,
                                                  u16* __restrict__ h4,
                                                  float* __restrict__ sum4, float* __restrict__ sq4) {
  __shared__ __align__(16) u16 lA[9728];     // 19 segs
  __shared__ __align__(16) u16 lB[10240];    // 20 segs
  const int tid = threadIdx.x;
  const int w = tid >> 6, l = tid & 63;
  const int lm = l & 15, lk = l >> 4;
  const int b = blockIdx.x >> 4;
  const int y0 = (blockIdx.x & 15) << 2;
  const int y = y0 + w;
  const u16* src = h3p + ((size_t)b * 66 + y0) * RP2;
  for (int seg = w; seg < 19; seg += 4) cp16(src + seg * 512 + l * 8, lA + seg * 512);
  for (int seg = w; seg < 20; seg += 4) cp16(Bsw4 + seg * 512 + l * 8, lB + seg * 512);
  __syncthreads();

  floatx4 acc[4][4];
#pragma unroll
  for (int mt = 0; mt < 4; ++mt)
#pragma unroll
    for (int nb = 0; nb < 4; ++nb)
      acc[mt][nb] = (floatx4){0.f, 0.f, 0.f, 0.f};

#pragma unroll
  for (int kk = 0; kk < 5; ++kk) {
    int tap = kk * 2 + (lk >> 1);
    if (tap > 8) tap = 8;
    const int dy = tap / 3, dx = tap - dy * 3;
    const int c0 = (lk & 1) << 3;
    const int rowoff = (w + dy) * RP2;
    short8 aF[4], bF[4];
#pragma unroll
    for (int mt = 0; mt < 4; ++mt)
      aF[mt] = *(const short8*)(lA + rowoff + (mt * 16 + lm + dx) * 24 + c0);
    const u16* bp = lB + (((kk * 4 + lk) * 64) + lm) * 8;
    bF[0] = *(const short8*)(bp);
    bF[1] = *(const short8*)(bp + 128);
    bF[2] = *(const short8*)(bp + 256);
    bF[3] = *(const short8*)(bp + 384);
#pragma unroll
    for (int mt = 0; mt < 4; ++mt)
#pragma unroll
      for (int nb = 0; nb < 4; ++nb)
        acc[mt][nb] = __builtin_amdgcn_mfma_f32_16x16x32_bf16(aF[mt], bF[nb], acc[mt][nb], 0, 0, 0);
  }

#pragma unroll
  for (int mt = 0; mt < 4; ++mt)
#pragma unroll
    for (int nb = 0; nb < 4; ++nb) {
      u16* dst = h4 + ((size_t)(b * 64 + nb * 16 + lm) << 12) + (y << 6) + mt * 16 + (lk << 2);
      floatx4 v = acc[mt][nb];
      *(ushort4*)dst = make_ushort4(f2bf(v.x), f2bf(v.y), f2bf(v.z), f2bf(v.w));
    }

  // fused stats4 (reuse lA after barrier)
  __syncthreads();
  float* LS = (float*)lA;
  float* LQ = LS + 256;
  float s[4], s2[4];
#pragma unroll
  for (int nb = 0; nb < 4; ++nb) {
    s[nb] = 0.f; s2[nb] = 0.f;
#pragma unroll
    for (int mt = 0; mt < 4; ++mt) {
      floatx4 a = acc[mt][nb];
      s[nb] += a.x + a.y + a.z + a.w;
      s2[nb] += a.x * a.x + a.y * a.y + a.z * a.z + a.w * a.w;
    }
    s[nb] += __shfl_xor(s[nb], 16, 64);  s[nb] += __shfl_xor(s[nb], 32, 64);
    s2[nb] += __shfl_xor(s2[nb], 16, 64); s2[nb] += __shfl_xor(s2[nb], 32, 64);
  }
  if (lk == 0) {
#pragma unroll
    for (int nb = 0; nb < 4; ++nb) { LS[w * 64 + nb * 16 + lm] = s[nb]; LQ[w * 64 + nb * 16 + lm] = s2[nb]; }
  }
  __syncthreads();
  if (tid < 64) atomicAdd(&sum4[tid], LS[tid] + LS[64 + tid] + LS[128 + tid] + LS[192 + tid]);
  else if (tid < 128) { int o = tid - 64; atomicAdd(&sq4[o], LQ[o] + LQ[64 + o] + LQ[128 + o] + LQ[192 + o]); }
}

// ---------------------------------------------------------------- final: BN4 + residual + relu (h4 bf16 -> out fp32), grid-stride
__global__ __launch_bounds__(256) void final_k(const u16* __restrict__ h4,
                                               float* __restrict__ out,
                                               const float* __restrict__ x,
                                               const float* __restrict__ sum4, const float* __restrict__ sq4,
                                               const float* __restrict__ g4, const float* __restrict__ b4) {
  __shared__ float s_scale[64], s_shift[64];
  int tid = threadIdx.x;
  if (tid < 64) {
    float m = sum4[tid] / BN_N;
    float var = sq4[tid] / BN_N - m * m;
    float sc = g4[tid] * rsqrtf(var + 1e-5f);
    s_scale[tid] = sc;
    s_shift[tid] = b4[tid] - m * sc;
  }
  __syncthreads();
  // 16,777,216 floats = 4,194,304 float4; 2048 blocks x 256 thr -> 8 iters
  int t0 = blockIdx.x * 256 + tid;
#pragma unroll
  for (int it = 0; it < 8; ++it) {
    int i = (t0 + it * 524288) * 4;
    int c = (i >> 12) & 63;
    ushort4 q = *(const ushort4*)(h4 + i);
    float4 xv = *(const float4*)(x + i);
    float sc = s_scale[c], sh = s_shift[c];
    float4 v;
    v.x = fmaxf(bf2f(q.x) * sc + sh + xv.x, 0.f);
    v.y = fmaxf(bf2f(q.y) * sc + sh + xv.y, 0.f);
    v.z = fmaxf(bf2f(q.z) * sc + sh + xv.z, 0.f);
    v.w = fmaxf(bf2f(q.w) * sc + sh + xv.w, 0.f);
    *(float4*)(out + i) = v;
  }
}

extern "C" void kernel_launch(void* const* d_in, const int* in_sizes, int n_in,
                              void* d_out, int out_size, void* d_ws, size_t ws_size,
                              hipStream_t stream) {
  const float* x  = (const float*)d_in[0];
  const float* w1 = (const float*)d_in[1];
  const float* g1 = (const float*)d_in[2];
  const float* b1 = (const float*)d_in[3];
  const float* w2 = (const float*)d_in[4];
  const float* g2 = (const float*)d_in[5];
  const float* b2 = (const float*)d_in[6];
  const float* ow = (const float*)d_in[7];
  const float* ob = (const float*)d_in[8];
  const float* w3 = (const float*)d_in[9];
  const float* g3 = (const float*)d_in[10];
  const float* b3 = (const float*)d_in[11];
  const float* w4 = (const float*)d_in[12];
  const float* g4 = (const float*)d_in[13];
  const float* b4 = (const float*)d_in[14];
  float* out = (float*)d_out;
  float* ws = (float*)d_ws;

  // workspace layout (float offsets) — regions keep fp32-era sizes, some hold
  // bf16 (half-used):
  //   reg0 (ex-offs, 4,718,592 floats): h4 (bf16 NCHW conv4 raw) overlays
  //   wsd  region (4,194,304): bf16 NHWC deform raw (uses half)
  //   ws2  region (4,194,304): bf16 NHWC conv2 raw (uses half)
  //   h2p  region (4,460,544): padded pitch-24 bf16; h3p SHARES it
  //   stats 320
  //   Bsw(36864) Bsw4(10240) Bsw3(2560) BswO(5120)  u16
  // xp (swizzled bf16 input, 17.8M u16) overlays reg0+wsd+ws2 head; dead
  // after conv1.  h1 (bf16 NCHW conv1 raw) lives in d_out.
  float* reg0 = ws;
  float* wsd  = reg0 + 4718592;
  float* ws2  = wsd + 4194304;
  float* h2pf = ws2 + 4194304;
  float* stats = h2pf + 4460544;
  float* sum1 = stats, *sq1 = stats + 64;
  float* sum2 = stats + 128, *sq2 = stats + 144;
  float* sum3 = stats + 160, *sq3 = stats + 176;
  float* sum4 = stats + 192, *sq4 = stats + 256;
  u16* xp   = (u16*)ws;
  u16* Bsw  = (u16*)(stats + 320);
  u16* Bsw4 = Bsw + 36864;
  u16* Bsw3 = Bsw4 + 10240;
  u16* BswO = Bsw3 + 2560;
  u16* h2p  = (u16*)h2pf;    // bf16 padded pitch-24; doubles as h3p
  u16* h4   = (u16*)reg0;    // bf16 NCHW conv4 raw
  u16* h1   = (u16*)out;     // bf16 NCHW conv1 raw, in d_out
  u16* ws2b = (u16*)ws2;     // bf16 NHWC conv2 raw
  u16* wsdb = (u16*)wsd;     // bf16 NHWC deform raw

  hipMemsetAsync(stats, 0, 320 * sizeof(float), stream);
  hipMemsetAsync(h2p, 0, (size_t)H2P_TOTAL * sizeof(u16), stream);

  prep_all_k<<<4438, 256, 0, stream>>>(x, xp, w1, w4, w3, ow, Bsw, Bsw4, Bsw3, BswO);
  conv1_mfma<<<256, 512, 0, stream>>>(xp, Bsw, h1, sum1, sq1);
  conv2_k<<<1024, 256, 0, stream>>>(h1, w2, sum1, sq1, g1, b1, ws2b, sum2, sq2);
  bnrelu2_k<<<1024, 256, 0, stream>>>(ws2b, sum2, sq2, g2, b2, h2p);
  offdeform_mfma<<<1024, 256, 0, stream>>>(h2p, BswO, ob, Bsw3, wsdb, sum3, sq3);
  bnrelu3_k<<<1024, 256, 0, stream>>>(wsdb, sum3, sq3, g3, b3, h2p /* = h3p */);
  conv4_mfma<<<1024, 256, 0, stream>>>(h2p, Bsw4, h4, sum4, sq4);
  final_k<<<2048, 256, 0, stream>>>(h4, out, x, sum4, sq4, g4, b4);
}

// Round 13
// 305.583 us; speedup vs baseline: 1.0129x; 1.0106x over previous
//
#include <hip/hip_runtime.h>

// B=64, Cin=P=64, H=W=64, mid C=16, offsets C=18, K=3x3.  BN n = 262144
#define BN_N 262144.0f

typedef unsigned short u16;
typedef __attribute__((ext_vector_type(8))) short short8;   // 8 x bf16
typedef __attribute__((ext_vector_type(4))) float floatx4;

// xp: padded NHWC bf16, 64 ch/px, XOR-swizzled 16B chunks. Row pitch 66*64.
#define RP1 4224
#define IS1 278784          // 66*RP1
// h2p/h3p: padded NHWC bf16, 16 ch/px padded to 24 (2-way LDS banks). Row pitch 66*24.
#define RP2 1584
#define IS2 104544          // 66*RP2
#define H2P_TOTAL 6690816   // 64*IS2 u16

static __device__ __forceinline__ u16 f2bf(float f) {
  union { float f; unsigned u; } v; v.f = f;
  unsigned u = v.u;
  return (u16)((u + 0x7FFFu + ((u >> 16) & 1u)) >> 16);
}
static __device__ __forceinline__ float bf2f(u16 h) {
  union { unsigned u; float f; } v; v.u = ((unsigned)h) << 16;
  return v.f;
}
// async global->LDS, 16 B per lane; LDS dest = wave-uniform base + lane*16
static __device__ __forceinline__ void cp16(const u16* g, u16* l) {
  __builtin_amdgcn_global_load_lds((const __attribute__((address_space(1))) unsigned int*)g,
                                   (__attribute__((address_space(3))) unsigned int*)l, 16, 0, 0);
}

// ---------------------------------------------------------------- prep: x -> padded swizzled bf16  +  all weights (merged launch)
// Blocks 0..4223: prep_x (yp = blk%66, b = blk/66).  Blocks 4224..4437:
// weight repack (early return, no barrier crossed).
__global__ __launch_bounds__(256) void prep_all_k(const float* __restrict__ x,
                                                  u16* __restrict__ xp,
                                                  const float* __restrict__ w1,
                                                  const float* __restrict__ w4,
                                                  const float* __restrict__ w3,
                                                  const float* __restrict__ ow,
                                                  u16* __restrict__ Bsw, u16* __restrict__ Bsw4,
                                                  u16* __restrict__ Bsw3, u16* __restrict__ BswO) {
  int blk = blockIdx.x, tid = threadIdx.x;
  if (blk >= 4224) {                       // ---- weight repack blocks ----
    int wb = blk - 4224;
    if (wb < 144) {                        // conv1: K=576, 36864 elems
      int d = wb * 256 + tid;
      int kin = d & 7, n = (d >> 3) & 63, kgrp = (d >> 9) & 3, kc = d >> 11;
      int k = kc * 32 + kgrp * 8 + kin;
      int tap = k >> 6, c = k & 63;
      Bsw[d] = f2bf(w1[n * 576 + c * 9 + tap]);
    } else if (wb < 184) {                 // conv4: K=144->160, 10240 elems
      int d = (wb - 144) * 256 + tid;
      int kin = d & 7, n = (d >> 3) & 63, lkk = (d >> 9) & 3, kk = d >> 11;
      int tap = kk * 2 + (lkk >> 1);
      int c = ((lkk & 1) << 3) + kin;
      float v = (tap < 9) ? w4[n * 144 + c * 9 + tap] : 0.f;
      Bsw4[d] = f2bf(v);
    } else if (wb < 194) {                 // deform w3: 2560 elems
      int d = (wb - 184) * 256 + tid;
      int kin = d & 7, n = (d >> 3) & 15, lkk = (d >> 7) & 3, kk = d >> 9;
      int k = kk * 32 + lkk * 8 + kin;
      int tap = k >> 4, c = k & 15;
      float v = (tap < 9) ? w3[n * 144 + c * 9 + tap] : 0.f;
      Bsw3[d] = f2bf(v);
    } else {                               // offconv: 5120 elems
      int d = (wb - 194) * 256 + tid;
      int kin = d & 7, n = (d >> 3) & 31, lkk = (d >> 8) & 3, kk = d >> 10;
      int tap = kk * 2 + (lkk >> 1);
      int c = ((lkk & 1) << 3) + kin;
      float v = (tap < 9 && n < 18) ? ow[n * 144 + c * 9 + tap] : 0.f;
      BswO[d] = f2bf(v);
    }
    return;
  }
  // ---- prep_x blocks ----
  int yp = blk % 66;
  int b = blk / 66;
  u16* rowbase = xp + (size_t)(b * 66 + yp) * RP1;
  if (yp == 0 || yp == 65) {
    for (int i = tid; i < RP1 / 4; i += 256)
      ((ushort4*)rowbase)[i] = make_ushort4(0, 0, 0, 0);
    return;
  }
  int y = yp - 1;
  __shared__ __align__(16) u16 s[64][72];
  for (int i = tid; i < 4096; i += 256) {
    int c = i >> 6, xx = i & 63;
    s[xx][c] = f2bf(x[((b * 64 + c) << 12) + (y << 6) + xx]);
  }
  if (tid < 128) {                 // zero pad columns (px 0 and 65)
    int c = tid & 63;
    int pxp = (tid >> 6) ? 65 : 0;
    rowbase[pxp * 64 + c] = 0;
  }
  __syncthreads();
  for (int j = tid; j < 512; j += 256) {       // 64 px x 8 chunks of 16 B
    int xx = j >> 3, chunk = j & 7;
    int pxp = xx + 1;
    int ph = chunk ^ (pxp & 7);
    *(short8*)(rowbase + pxp * 64 + ph * 8) = *(const short8*)(&s[xx][chunk * 8]);
  }
}

// ---------------------------------------------------------------- conv1: persistent ring pipeline, 8 waves (2/SIMD), B in regs
__global__ __launch_bounds__(512, 2) void conv1_mfma(const u16* __restrict__ xp,
                                                     const u16* __restrict__ Bsw,
                                                     u16* __restrict__ h1,        // bf16 NCHW raw
                                                     float* __restrict__ sum1, float* __restrict__ sq1) {
  __shared__ __align__(16) u16 ring[43520];   // 5 slots x 8704 u16 (2 rows + 512B overread pad)
  __shared__ float LS[256], LQ[256];          // stats scratch [4 rows][64 oc]
  const int tid = threadIdx.x;
  const int w8 = tid >> 6, l = tid & 63;
  const int r = w8 & 3, g = w8 >> 2;          // row-in-tile, oc-half
  const int lm = l & 15, lk = l >> 4;
  const int b = blockIdx.x >> 2;
  const int quarter = blockIdx.x & 3;
  const int c0 = quarter * 8;                 // first 2-row chunk of this band
  const u16* xb = xp + (size_t)b * 66 * RP1;

  // B fragments -> registers, ONCE (oldest VMEM ops; prologue vmcnt(0) covers them)
  short8 bReg[18][2];
#pragma unroll
  for (int kk = 0; kk < 18; ++kk)
#pragma unroll
    for (int j = 0; j < 2; ++j)
      bReg[kk][j] = *(const short8*)(Bsw + (((kk * 4 + lk) * 64) + (g * 2 + j) * 16 + lm) * 8);

  // prologue: A chunks c0..c0+2 (3 x 17 segs); drain + barrier
#pragma unroll
  for (int c = 0; c < 3; ++c) {
    const u16* src = xb + (size_t)(2 * (c0 + c)) * RP1;
    u16* dst = ring + ((c0 + c) % 5) * 8704;
    for (int s = w8; s < 17; s += 8) cp16(src + s * 512 + l * 8, dst + s * 512);
  }
  asm volatile("s_waitcnt vmcnt(0)" ::: "memory");
  __builtin_amdgcn_s_barrier();
  __builtin_amdgcn_sched_barrier(0);

  float ssum[2] = {0.f, 0.f}, sqsm[2] = {0.f, 0.f};

#pragma unroll 1
  for (int j = 0; j < 4; ++j) {
    const int y0 = quarter * 16 + j * 4;
    // prefetch next tile's 2 new chunks (ring-5 liveness: disjoint slots)
    if (j < 3) {
#pragma unroll
      for (int c = 0; c < 2; ++c) {
        const int ch = c0 + 2 * j + 3 + c;
        const u16* src = xb + (size_t)(2 * ch) * RP1;
        u16* dst = ring + (ch % 5) * 8704;
        for (int s = w8; s < 17; s += 8) cp16(src + s * 512 + l * 8, dst + s * 512);
      }
      __builtin_amdgcn_sched_barrier(0);   // pin prefetch before stores
    }

    floatx4 acc[4][2];
#pragma unroll
    for (int mt = 0; mt < 4; ++mt)
#pragma unroll
      for (int nb = 0; nb < 2; ++nb)
        acc[mt][nb] = (floatx4){0.f, 0.f, 0.f, 0.f};

#pragma unroll
    for (int kk = 0; kk < 18; ++kk) {
      const int tap = kk >> 1;
      const int dy = (tap < 3) ? 0 : ((tap < 6) ? 1 : 2);
      const int dx = tap - dy * 3;
      const int chunk16 = ((kk & 1) << 2) + lk;   // logical 16B chunk 0..7
      const int pr = y0 + r + dy;                 // padded input row
      const u16* abase = ring + ((pr >> 1) % 5) * 8704 + (pr & 1) * 4224;
      short8 aF[4];
#pragma unroll
      for (int mt = 0; mt < 4; ++mt) {
        int pxp = mt * 16 + lm + dx;
        int ph = chunk16 ^ (pxp & 7);
        aF[mt] = *(const short8*)(abase + pxp * 64 + ph * 8);
      }
#pragma unroll
      for (int mt = 0; mt < 4; ++mt)
#pragma unroll
        for (int nb = 0; nb < 2; ++nb)
          acc[mt][nb] = __builtin_amdgcn_mfma_f32_16x16x32_bf16(aF[mt], bReg[kk][nb], acc[mt][nb], 0, 0, 0);
    }

    // store bf16 NCHW: oc = g*32 + nb*16 + lm, pixel x = mt*16 + lk*4 + reg (8 stores)
    const int y = y0 + r;
#pragma unroll
    for (int mt = 0; mt < 4; ++mt)
#pragma unroll
      for (int nb = 0; nb < 2; ++nb) {
        const int oc = g * 32 + nb * 16 + lm;
        u16* dst = h1 + ((size_t)(b * 64 + oc) << 12) + (y << 6) + mt * 16 + (lk << 2);
        floatx4 v = acc[mt][nb];
        *(ushort4*)dst = make_ushort4(f2bf(v.x), f2bf(v.y), f2bf(v.z), f2bf(v.w));
      }

    // per-tile stats into running registers
#pragma unroll
    for (int nb = 0; nb < 2; ++nb)
#pragma unroll
      for (int mt = 0; mt < 4; ++mt) {
        floatx4 a = acc[mt][nb];
        ssum[nb] += a.x + a.y + a.z + a.w;
        sqsm[nb] += a.x * a.x + a.y * a.y + a.z * a.z + a.w * a.w;
      }

    if (j < 3) {
      asm volatile("s_waitcnt vmcnt(8)" ::: "memory");
      __builtin_amdgcn_s_barrier();
      __builtin_amdgcn_sched_barrier(0);
    }
  }

  // final stats reduction (once per block)
#pragma unroll
  for (int nb = 0; nb < 2; ++nb) {
    ssum[nb] += __shfl_xor(ssum[nb], 16, 64);  ssum[nb] += __shfl_xor(ssum[nb], 32, 64);
    sqsm[nb] += __shfl_xor(sqsm[nb], 16, 64);  sqsm[nb] += __shfl_xor(sqsm[nb], 32, 64);
  }
  if (lk == 0) {
#pragma unroll
    for (int nb = 0; nb < 2; ++nb) {
      const int oc = g * 32 + nb * 16 + lm;
      LS[r * 64 + oc] = ssum[nb];  LQ[r * 64 + oc] = sqsm[nb];
    }
  }
  __syncthreads();
  if (tid < 64) atomicAdd(&sum1[tid], LS[tid] + LS[64 + tid] + LS[128 + tid] + LS[192 + tid]);
  else if (tid < 128) { int o = tid - 64; atomicAdd(&sq1[o], LQ[o] + LQ[64 + o] + LQ[128 + o] + LQ[192 + o]); }
}

// ---------------------------------------------------------------- conv2: 1x1 64->16 (bf16 h1 in), BN1+relu, bf16 NHWC out + stats2
__global__ __launch_bounds__(256) void conv2_k(const u16* __restrict__ h1,
                                               const float* __restrict__ w2,
                                               const float* __restrict__ sum1, const float* __restrict__ sq1,
                                               const float* __restrict__ g1, const float* __restrict__ b1,
                                               u16* __restrict__ out,          // bf16 NHWC (64,4096,16) raw
                                               float* __restrict__ sum2, float* __restrict__ sq2) {
  __shared__ float s_wt[64 * 16];
  __shared__ float s_scale[64], s_shift[64];
  __shared__ float ls[4][16], lsq[4][16];
  int tid = threadIdx.x;
  for (int i = tid; i < 1024; i += 256) {
    int o = i >> 6, c = i & 63;
    s_wt[c * 16 + o] = w2[i];
  }
  if (tid < 64) {
    float m = sum1[tid] / BN_N;
    float var = sq1[tid] / BN_N - m * m;
    float sc = g1[tid] * rsqrtf(var + 1e-5f);
    s_scale[tid] = sc;
    s_shift[tid] = b1[tid] - m * sc;
  }
  __syncthreads();
  int p = blockIdx.x * 256 + tid;
  int b = p >> 12, r = p & 4095;
  const u16* src = h1 + ((size_t)b << 18) + r;
  float acc[16];
#pragma unroll
  for (int o = 0; o < 16; ++o) acc[o] = 0.f;
  for (int c = 0; c < 64; ++c) {
    float v = bf2f(src[c << 12]);
    v = fmaxf(v * s_scale[c] + s_shift[c], 0.f);
    const float* wp = &s_wt[c * 16];
    float4 w0 = *(const float4*)wp;
    float4 w1 = *(const float4*)(wp + 4);
    float4 w2v = *(const float4*)(wp + 8);
    float4 w3v = *(const float4*)(wp + 12);
    acc[0] += w0.x * v;  acc[1] += w0.y * v;  acc[2] += w0.z * v;  acc[3] += w0.w * v;
    acc[4] += w1.x * v;  acc[5] += w1.y * v;  acc[6] += w1.z * v;  acc[7] += w1.w * v;
    acc[8] += w2v.x * v; acc[9] += w2v.y * v; acc[10] += w2v.z * v; acc[11] += w2v.w * v;
    acc[12] += w3v.x * v; acc[13] += w3v.y * v; acc[14] += w3v.z * v; acc[15] += w3v.w * v;
  }
  u16* dst = out + (size_t)p * 16;
  short8 o0, o1;
#pragma unroll
  for (int j = 0; j < 8; ++j) {
    o0[j] = (short)f2bf(acc[j]);
    o1[j] = (short)f2bf(acc[8 + j]);
  }
  *(short8*)(dst) = o0;
  *(short8*)(dst + 8) = o1;
  int lane = tid & 63, wv = tid >> 6;
#pragma unroll
  for (int o = 0; o < 16; ++o) {
    float s = acc[o], s2 = acc[o] * acc[o];
#pragma unroll
    for (int off = 32; off > 0; off >>= 1) {
      s += __shfl_down(s, off, 64);
      s2 += __shfl_down(s2, off, 64);
    }
    if (lane == 0) { ls[wv][o] = s; lsq[wv][o] = s2; }
  }
  __syncthreads();
  if (tid < 16) atomicAdd(&sum2[tid], ls[0][tid] + ls[1][tid] + ls[2][tid] + ls[3][tid]);
  else if (tid < 32) {
    int o = tid - 16;
    atomicAdd(&sq2[o], lsq[0][o] + lsq[1][o] + lsq[2][o] + lsq[3][o]);
  }
}

// ---------------------------------------------------------------- BN2+relu: bf16 NHWC raw -> padded pitch-24 bf16 h2p
__global__ __launch_bounds__(256) void bnrelu2_k(const u16* __restrict__ ws2,
                                                 const float* __restrict__ sum2, const float* __restrict__ sq2,
                                                 const float* __restrict__ g2, const float* __restrict__ b2,
                                                 u16* __restrict__ h2p) {
  __shared__ float s_scale[16], s_shift[16];
  int tid = threadIdx.x;
  if (tid < 16) {
    float m = sum2[tid] / BN_N;
    float var = sq2[tid] / BN_N - m * m;
    float sc = g2[tid] * rsqrtf(var + 1e-5f);
    s_scale[tid] = sc;
    s_shift[tid] = b2[tid] - m * sc;
  }
  __syncthreads();
  int p = blockIdx.x * 256 + tid;
  int b = p >> 12, r = p & 4095;
  int y = r >> 6, xx = r & 63;
  const u16* src = ws2 + (size_t)p * 16;
  short8 v0 = *(const short8*)(src);
  short8 v1 = *(const short8*)(src + 8);
  u16* dst = h2p + (size_t)(b * 66 + y + 1) * RP2 + (xx + 1) * 24;
  short8 o0, o1;
#pragma unroll
  for (int j = 0; j < 8; ++j) {
    o0[j] = (short)f2bf(fmaxf(bf2f((u16)v0[j]) * s_scale[j] + s_shift[j], 0.f));
    o1[j] = (short)f2bf(fmaxf(bf2f((u16)v1[j]) * s_scale[j + 8] + s_shift[j + 8], 0.f));
  }
  *(short8*)(dst) = o0;
  *(short8*)(dst + 8) = o1;
}

// ---------------------------------------------------------------- fused offconv + deform: offsets hand off via LDS
__global__ __launch_bounds__(256) void offdeform_mfma(const u16* __restrict__ h2p,
                                                      const u16* __restrict__ BswO,
                                                      const float* __restrict__ ob,
                                                      const u16* __restrict__ Bsw3,
                                                      u16* __restrict__ out,      // bf16 NHWC (64,4096,16) raw
                                                      float* __restrict__ sum3, float* __restrict__ sq3) {
  __shared__ __align__(16) u16 lA[9728];    // 19 segs (6 rows pitch-24 + overread)
  __shared__ __align__(16) u16 lB[5120];    // 10 segs
  __shared__ float offsT[4][64][20];        // [row][x][oc(18, pad 20)]
  __shared__ float ls[4][16], lsq[4][16];
  const int tid = threadIdx.x;
  const int w = tid >> 6, l = tid & 63;
  const int lm = l & 15, lk = l >> 4;
  const int b = blockIdx.x >> 4;
  const int y0 = (blockIdx.x & 15) << 2;
  const int y = y0 + w;
  const u16* src = h2p + ((size_t)b * 66 + y0) * RP2;
  for (int seg = w; seg < 19; seg += 4) cp16(src + seg * 512 + l * 8, lA + seg * 512);
  for (int seg = w; seg < 10; seg += 4) cp16(BswO + seg * 512 + l * 8, lB + seg * 512);
  __syncthreads();

  // ---- stage 1: offconv ----
  floatx4 acc[4][2];
#pragma unroll
  for (int mt = 0; mt < 4; ++mt)
#pragma unroll
    for (int nb = 0; nb < 2; ++nb)
      acc[mt][nb] = (floatx4){0.f, 0.f, 0.f, 0.f};

#pragma unroll
  for (int kk = 0; kk < 5; ++kk) {
    int tap = kk * 2 + (lk >> 1);
    if (tap > 8) tap = 8;
    const int dy = tap / 3, dx = tap - dy * 3;
    const int c0 = (lk & 1) << 3;
    const int rowoff = (w + dy) * RP2;
    short8 aF[4], bF[2];
#pragma unroll
    for (int mt = 0; mt < 4; ++mt)
      aF[mt] = *(const short8*)(lA + rowoff + (mt * 16 + lm + dx) * 24 + c0);
    const u16* bp = lB + (((kk * 4 + lk) * 32) + lm) * 8;
    bF[0] = *(const short8*)(bp);
    bF[1] = *(const short8*)(bp + 128);
#pragma unroll
    for (int mt = 0; mt < 4; ++mt)
#pragma unroll
      for (int nb = 0; nb < 2; ++nb)
        acc[mt][nb] = __builtin_amdgcn_mfma_f32_16x16x32_bf16(aF[mt], bF[nb], acc[mt][nb], 0, 0, 0);
  }

  // offsets (+bias) -> LDS.  D layout: pixel x = mt*16 + lk*4 + reg, oc = nb*16+lm
#pragma unroll
  for (int mt = 0; mt < 4; ++mt)
#pragma unroll
    for (int nb = 0; nb < 2; ++nb) {
      int oc = nb * 16 + lm;
      if (oc < 18) {
        float bias = ob[oc];
        floatx4 v = acc[mt][nb];
#pragma unroll
        for (int reg = 0; reg < 4; ++reg)
          offsT[w][mt * 16 + lk * 4 + reg][oc] = v[reg] + bias;
      }
    }
  __syncthreads();

  // ---- stage 2: deform ----
  const u16* img = h2p + (size_t)b * IS2;
  short8 bf[5];
#pragma unroll
  for (int kk = 0; kk < 5; ++kk)
    bf[kk] = *(const short8*)(Bsw3 + (((kk * 4 + lk) * 16) + lm) * 8);

  floatx4 accd[4];
#pragma unroll
  for (int mt = 0; mt < 4; ++mt) accd[mt] = (floatx4){0.f, 0.f, 0.f, 0.f};

#pragma unroll
  for (int mt = 0; mt < 4; ++mt) {
    const int x = mt * 16 + lm;          // A-side pixel of this lane
#pragma unroll
    for (int kk = 0; kk < 5; ++kk) {
      const int k0 = kk * 32 + lk * 8;
      int tap = k0 >> 4;
      const int c0 = k0 & 15;
      if (tap > 8) tap = 8;
      const int dy = tap / 3, dx = tap - dy * 3;
      float offy = offsT[w][x][tap];
      float offx = offsT[w][x][tap + 9];
      float py = (float)(y + dy) + offy;
      float px = (float)(x + dx) + offx;
      py = fminf(fmaxf(py, 0.f), 65.f);
      px = fminf(fmaxf(px, 0.f), 65.f);
      float y0f = floorf(py), x0f = floorf(px);
      int yy0 = (int)y0f, xx0 = (int)x0f;
      int yy1 = min(yy0 + 1, 65), xx1 = min(xx0 + 1, 65);
      float wy = py - y0f, wx = px - x0f;
      float w00 = (1.f - wy) * (1.f - wx), w01 = (1.f - wy) * wx;
      float w10 = wy * (1.f - wx),         w11 = wy * wx;
      short8 v00 = *(const short8*)(img + (yy0 * 66 + xx0) * 24 + c0);
      short8 v01 = *(const short8*)(img + (yy0 * 66 + xx1) * 24 + c0);
      short8 v10 = *(const short8*)(img + (yy1 * 66 + xx0) * 24 + c0);
      short8 v11 = *(const short8*)(img + (yy1 * 66 + xx1) * 24 + c0);
      short8 a;
#pragma unroll
      for (int jj = 0; jj < 8; ++jj) {
        float s = bf2f((u16)v00[jj]) * w00 + bf2f((u16)v01[jj]) * w01
                + bf2f((u16)v10[jj]) * w10 + bf2f((u16)v11[jj]) * w11;
        a[jj] = (short)f2bf(s);
      }
      accd[mt] = __builtin_amdgcn_mfma_f32_16x16x32_bf16(a, bf[kk], accd[mt], 0, 0, 0);
    }
  }

  // store bf16 NHWC raw: pixel = mt*16 + lk*4 + reg, channel = lm; + stats
  const int pbase = (b << 12) + (y << 6);
  float s = 0.f, s2 = 0.f;
#pragma unroll
  for (int mt = 0; mt < 4; ++mt) {
    floatx4 a = accd[mt];
    s += a.x + a.y + a.z + a.w;
    s2 += a.x * a.x + a.y * a.y + a.z * a.z + a.w * a.w;
#pragma unroll
    for (int reg = 0; reg < 4; ++reg) {
      int pp = pbase + mt * 16 + lk * 4 + reg;
      out[(size_t)pp * 16 + lm] = f2bf(a[reg]);
    }
  }
  s += __shfl_xor(s, 16, 64);  s += __shfl_xor(s, 32, 64);
  s2 += __shfl_xor(s2, 16, 64); s2 += __shfl_xor(s2, 32, 64);
  if (lk == 0) { ls[w][lm] = s; lsq[w][lm] = s2; }
  __syncthreads();
  if (tid < 16) atomicAdd(&sum3[tid], ls[0][tid] + ls[1][tid] + ls[2][tid] + ls[3][tid]);
  else if (tid < 32) {
    int o = tid - 16;
    atomicAdd(&sq3[o], lsq[0][o] + lsq[1][o] + lsq[2][o] + lsq[3][o]);
  }
}

// ---------------------------------------------------------------- BN3+relu: bf16 NHWC raw -> padded pitch-24 bf16 h3p
__global__ __launch_bounds__(256) void bnrelu3_k(const u16* __restrict__ wsd,
                                                 const float* __restrict__ sum3, const float* __restrict__ sq3,
                                                 const float* __restrict__ g3, const float* __restrict__ b3,
                                                 u16* __restrict__ h3p) {
  __shared__ float s_scale[16], s_shift[16];
  int tid = threadIdx.x;
  if (tid < 16) {
    float m = sum3[tid] / BN_N;
    float var = sq3[tid] / BN_N - m * m;
    float sc = g3[tid] * rsqrtf(var + 1e-5f);
    s_scale[tid] = sc;
    s_shift[tid] = b3[tid] - m * sc;
  }
  __syncthreads();
  int p = blockIdx.x * 256 + tid;
  int b = p >> 12, r = p & 4095;
  int y = r >> 6, xx = r & 63;
  const u16* src = wsd + (size_t)p * 16;
  short8 v0 = *(const short8*)(src);
  short8 v1 = *(const short8*)(src + 8);
  u16* dst = h3p + (size_t)(b * 66 + y + 1) * RP2 + (xx + 1) * 24;
  short8 o0, o1;
#pragma unroll
  for (int j = 0; j < 8; ++j) {
    o0[j] = (short)f2bf(fmaxf(bf2f((u16)v0[j]) * s_scale[j] + s_shift[j], 0.f));
    o1[j] = (short)f2bf(fmaxf(bf2f((u16)v1[j]) * s_scale[j + 8] + s_shift[j + 8], 0.f));
  }
  *(short8*)(dst) = o0;
  *(short8*)(dst + 8) = o1;
}

// ---------------------------------------------------------------- conv4: LDS-staged implicit GEMM (A+B in LDS) + stats4
__global__ __launch_bounds__(256) void conv4_mfma(const u16* __restrict__ h3p,
                                                  const u16* __restrict__ Bsw4,
                                                  u16* __restrict__ h4,
                                                  float* __restrict__ sum4, float* __restrict__ sq4) {
  __shared__ __align__(16) u16 lA[9728];     // 19 segs
  __shared__ __align__(16) u16 lB[10240];    // 20 segs
  const int tid = threadIdx.x;
  const int w = tid >> 6, l = tid & 63;
  const int lm = l & 15, lk = l >> 4;
  const int b = blockIdx.x >> 4;
  const int y0 = (blockIdx.x & 15) << 2;
  const int y = y0 + w;
  const u16* src = h3p + ((size_t)b * 66 + y0) * RP2;
  for (int seg = w; seg < 19; seg += 4) cp16(src + seg * 512 + l * 8, lA + seg * 512);
  for (int seg = w; seg < 20; seg += 4) cp16(Bsw4 + seg * 512 + l * 8, lB + seg * 512);
  __syncthreads();

  floatx4 acc[4][4];
#pragma unroll
  for (int mt = 0; mt < 4; ++mt)
#pragma unroll
    for (int nb = 0; nb < 4; ++nb)
      acc[mt][nb] = (floatx4){0.f, 0.f, 0.f, 0.f};

#pragma unroll
  for (int kk = 0; kk < 5; ++kk) {
    int tap = kk * 2 + (lk >> 1);
    if (tap > 8) tap = 8;
    const int dy = tap / 3, dx = tap - dy * 3;
    const int c0 = (lk & 1) << 3;
    const int rowoff = (w + dy) * RP2;
    short8 aF[4], bF[4];
#pragma unroll
    for (int mt = 0; mt < 4; ++mt)
      aF[mt] = *(const short8*)(lA + rowoff + (mt * 16 + lm + dx) * 24 + c0);
    const u16* bp = lB + (((kk * 4 + lk) * 64) + lm) * 8;
    bF[0] = *(const short8*)(bp);
    bF[1] = *(const short8*)(bp + 128);
    bF[2] = *(const short8*)(bp + 256);
    bF[3] = *(const short8*)(bp + 384);
#pragma unroll
    for (int mt = 0; mt < 4; ++mt)
#pragma unroll
      for (int nb = 0; nb < 4; ++nb)
        acc[mt][nb] = __builtin_amdgcn_mfma_f32_16x16x32_bf16(aF[mt], bF[nb], acc[mt][nb], 0, 0, 0);
  }

#pragma unroll
  for (int mt = 0; mt < 4; ++mt)
#pragma unroll
    for (int nb = 0; nb < 4; ++nb) {
      u16* dst = h4 + ((size_t)(b * 64 + nb * 16 + lm) << 12) + (y << 6) + mt * 16 + (lk << 2);
      floatx4 v = acc[mt][nb];
      *(ushort4*)dst = make_ushort4(f2bf(v.x), f2bf(v.y), f2bf(v.z), f2bf(v.w));
    }

  // fused stats4 (reuse lA after barrier)
  __syncthreads();
  float* LS = (float*)lA;
  float* LQ = LS + 256;
  float s[4], s2[4];
#pragma unroll
  for (int nb = 0; nb < 4; ++nb) {
    s[nb] = 0.f; s2[nb] = 0.f;
#pragma unroll
    for (int mt = 0; mt < 4; ++mt) {
      floatx4 a = acc[mt][nb];
      s[nb] += a.x + a.y + a.z + a.w;
      s2[nb] += a.x * a.x + a.y * a.y + a.z * a.z + a.w * a.w;
    }
    s[nb] += __shfl_xor(s[nb], 16, 64);  s[nb] += __shfl_xor(s[nb], 32, 64);
    s2[nb] += __shfl_xor(s2[nb], 16, 64); s2[nb] += __shfl_xor(s2[nb], 32, 64);
  }
  if (lk == 0) {
#pragma unroll
    for (int nb = 0; nb < 4; ++nb) { LS[w * 64 + nb * 16 + lm] = s[nb]; LQ[w * 64 + nb * 16 + lm] = s2[nb]; }
  }
  __syncthreads();
  if (tid < 64) atomicAdd(&sum4[tid], LS[tid] + LS[64 + tid] + LS[128 + tid] + LS[192 + tid]);
  else if (tid < 128) { int o = tid - 64; atomicAdd(&sq4[o], LQ[o] + LQ[64 + o] + LQ[128 + o] + LQ[192 + o]); }
}

// ---------------------------------------------------------------- final: BN4 + residual + relu (h4 bf16 -> out fp32), grid-stride
__global__ __launch_bounds__(256) void final_k(const u16* __restrict__ h4,
                                               float* __restrict__ out,
                                               const float* __restrict__ x,
                                               const float* __restrict__ sum4, const float* __restrict__ sq4,
                                               const float* __restrict__ g4, const float* __restrict__ b4) {
  __shared__ float s_scale[64], s_shift[64];
  int tid = threadIdx.x;
  if (tid < 64) {
    float m = sum4[tid] / BN_N;
    float var = sq4[tid] / BN_N - m * m;
    float sc = g4[tid] * rsqrtf(var + 1e-5f);
    s_scale[tid] = sc;
    s_shift[tid] = b4[tid] - m * sc;
  }
  __syncthreads();
  // 16,777,216 floats = 4,194,304 float4; 2048 blocks x 256 thr -> 8 iters
  int t0 = blockIdx.x * 256 + tid;
#pragma unroll
  for (int it = 0; it < 8; ++it) {
    int i = (t0 + it * 524288) * 4;
    int c = (i >> 12) & 63;
    ushort4 q = *(const ushort4*)(h4 + i);
    float4 xv = *(const float4*)(x + i);
    float sc = s_scale[c], sh = s_shift[c];
    float4 v;
    v.x = fmaxf(bf2f(q.x) * sc + sh + xv.x, 0.f);
    v.y = fmaxf(bf2f(q.y) * sc + sh + xv.y, 0.f);
    v.z = fmaxf(bf2f(q.z) * sc + sh + xv.z, 0.f);
    v.w = fmaxf(bf2f(q.w) * sc + sh + xv.w, 0.f);
    *(float4*)(out + i) = v;
  }
}

extern "C" void kernel_launch(void* const* d_in, const int* in_sizes, int n_in,
                              void* d_out, int out_size, void* d_ws, size_t ws_size,
                              hipStream_t stream) {
  const float* x  = (const float*)d_in[0];
  const float* w1 = (const float*)d_in[1];
  const float* g1 = (const float*)d_in[2];
  const float* b1 = (const float*)d_in[3];
  const float* w2 = (const float*)d_in[4];
  const float* g2 = (const float*)d_in[5];
  const float* b2 = (const float*)d_in[6];
  const float* ow = (const float*)d_in[7];
  const float* ob = (const float*)d_in[8];
  const float* w3 = (const float*)d_in[9];
  const float* g3 = (const float*)d_in[10];
  const float* b3 = (const float*)d_in[11];
  const float* w4 = (const float*)d_in[12];
  const float* g4 = (const float*)d_in[13];
  const float* b4 = (const float*)d_in[14];
  float* out = (float*)d_out;
  float* ws = (float*)d_ws;

  // workspace layout (float offsets) — regions keep fp32-era sizes, some hold
  // bf16 (half-used):
  //   reg0 (ex-offs, 4,718,592 floats): h4 (bf16 NCHW conv4 raw) overlays
  //   wsd  region (4,194,304): bf16 NHWC deform raw (uses half)
  //   ws2  region (4,194,304): bf16 NHWC conv2 raw (uses half)
  //   h2p  region (4,460,544): padded pitch-24 bf16; h3p SHARES it
  //   stats 320
  //   Bsw(36864) Bsw4(10240) Bsw3(2560) BswO(5120)  u16
  // xp (swizzled bf16 input, 17.8M u16) overlays reg0+wsd+ws2 head; dead
  // after conv1.  h1 (bf16 NCHW conv1 raw) lives in d_out.
  float* reg0 = ws;
  float* wsd  = reg0 + 4718592;
  float* ws2  = wsd + 4194304;
  float* h2pf = ws2 + 4194304;
  float* stats = h2pf + 4460544;
  float* sum1 = stats, *sq1 = stats + 64;
  float* sum2 = stats + 128, *sq2 = stats + 144;
  float* sum3 = stats + 160, *sq3 = stats + 176;
  float* sum4 = stats + 192, *sq4 = stats + 256;
  u16* xp   = (u16*)ws;
  u16* Bsw  = (u16*)(stats + 320);
  u16* Bsw4 = Bsw + 36864;
  u16* Bsw3 = Bsw4 + 10240;
  u16* BswO = Bsw3 + 2560;
  u16* h2p  = (u16*)h2pf;    // bf16 padded pitch-24; doubles as h3p
  u16* h4   = (u16*)reg0;    // bf16 NCHW conv4 raw
  u16* h1   = (u16*)out;     // bf16 NCHW conv1 raw, in d_out
  u16* ws2b = (u16*)ws2;     // bf16 NHWC conv2 raw
  u16* wsdb = (u16*)wsd;     // bf16 NHWC deform raw

  hipMemsetAsync(stats, 0, 320 * sizeof(float), stream);
  hipMemsetAsync(h2p, 0, (size_t)H2P_TOTAL * sizeof(u16), stream);

  prep_all_k<<<4438, 256, 0, stream>>>(x, xp, w1, w4, w3, ow, Bsw, Bsw4, Bsw3, BswO);
  conv1_mfma<<<256, 512, 0, stream>>>(xp, Bsw, h1, sum1, sq1);
  conv2_k<<<1024, 256, 0, stream>>>(h1, w2, sum1, sq1, g1, b1, ws2b, sum2, sq2);
  bnrelu2_k<<<1024, 256, 0, stream>>>(ws2b, sum2, sq2, g2, b2, h2p);
  offdeform_mfma<<<1024, 256, 0, stream>>>(h2p, BswO, ob, Bsw3, wsdb, sum3, sq3);
  bnrelu3_k<<<1024, 256, 0, stream>>>(wsdb, sum3, sq3, g3, b3, h2p /* = h3p */);
  conv4_mfma<<<1024, 256, 0, stream>>>(h2p, Bsw4, h4, sum4, sq4);
  final_k<<<2048, 256, 0, stream>>>(h4, out, x, sum4, sq4, g4, b4);
}